// Round 1
// baseline (1609.273 us; speedup 1.0000x reference)
//
#include <hip/hip_runtime.h>
#include <math.h>

#define BN_EPS 1e-3f

// cyl/bev constants (match reference; computed in double, cast to f32 like jnp would)
static constexpr float CR0 = -3.14159265f;
static constexpr float CR1 = -2.0f;
static constexpr float CVS0 = (float)((3.14159265 * 2.0) / 512.0);
static constexpr float CVS1 = (float)(6.0 / 48.0);
#define BEV_SXY (220 * 250)
#define BEV_SY 250

__device__ __forceinline__ float bnr(float x, float a, float b) {
    float v = fmaf(x, a, b);
    return v > 0.f ? v : 0.f;
}

// ---- weight transpose for conv: wc[o][i][kh][kw] -> wct[(kh*3+kw)][i][o] ----
__global__ void k_wct(const float* __restrict__ wc, float* __restrict__ wct) {
    int tid = blockIdx.x * blockDim.x + threadIdx.x;
    if (tid >= 9 * 64 * 64) return;
    int tap = tid / 4096;
    int rem = tid % 4096;
    int i = rem / 64;
    int o = rem % 64;
    int kh = tap / 3, kw = tap % 3;
    wct[tid] = wc[((o * 64 + i) * 3 + kh) * 3 + kw];
}

// ---- segment sums for means (bev: cnt,x,y ; cyl: cnt,phi,z) ----
__global__ void k_scatter_sums(const float* __restrict__ pts, const float* __restrict__ pcyl,
                               const int* __restrict__ binv, const int* __restrict__ cinv,
                               float* __restrict__ bacc, float* __restrict__ cacc,
                               int N, int Nb, int Nc) {
    int p = blockIdx.x * blockDim.x + threadIdx.x;
    if (p >= N) return;
    float x = pts[p * 5 + 1], y = pts[p * 5 + 2];
    float ph = pcyl[p * 3 + 0], z = pcyl[p * 3 + 1];
    int bi = binv[p], ci = cinv[p];
    atomicAdd(&bacc[bi], 1.0f);
    atomicAdd(&bacc[Nb + bi], x);
    atomicAdd(&bacc[2 * Nb + bi], y);
    atomicAdd(&cacc[ci], 1.0f);
    atomicAdd(&cacc[Nc + ci], ph);
    atomicAdd(&cacc[2 * Nc + ci], z);
}

// ---- build 16-dim feature + GEMM1 (16->64), h1 stored column-major (64 x N) ----
__global__ void k_feat_gemm1(const float* __restrict__ pts, const float* __restrict__ pcyl,
                             const float* __restrict__ cylidx, const float* __restrict__ bevidx,
                             const int* __restrict__ binv, const int* __restrict__ cinv,
                             const float* __restrict__ bacc, const float* __restrict__ cacc,
                             const float* __restrict__ w1, float* __restrict__ h1,
                             int N, int Nb, int Nc) {
    __shared__ float w1s[64 * 16];
    int t = threadIdx.x;
    for (int i = t; i < 1024; i += blockDim.x) w1s[i] = w1[i];
    __syncthreads();
    int p = blockIdx.x * blockDim.x + t;
    if (p >= N) return;
    float x = pts[p * 5 + 1], y = pts[p * 5 + 2], z = pts[p * 5 + 3], inten = pts[p * 5 + 4];
    float ph = pcyl[p * 3 + 0], zc = pcyl[p * 3 + 1], rho = pcyl[p * 3 + 2];
    float ci0 = cylidx[p * 2 + 0], ci1 = cylidx[p * 2 + 1];
    float bi0 = bevidx[p * 2 + 0], bi1 = bevidx[p * 2 + 1];
    float bc0 = floorf(bi0), bc1 = floorf(bi1);
    float cc0 = floorf(ci0), cc1 = floorf(ci1);
    int bv = binv[p], cv = cinv[p];
    float bcnt = bacc[bv];
    float bmx = bacc[Nb + bv] / bcnt, bmy = bacc[2 * Nb + bv] / bcnt;
    float ccnt = cacc[cv];
    float cmp = cacc[Nc + cv] / ccnt, cmz = cacc[2 * Nc + cv] / ccnt;
    float f[16];
    f[0] = x; f[1] = y; f[2] = z;
    f[3] = ph; f[4] = zc; f[5] = rho;
    f[6] = x - ((bc0 + 0.5f) * 0.32f + 0.0f);
    f[7] = y - ((bc1 + 0.5f) * 0.32f + (-40.0f));
    f[8] = ph - ((cc0 + 0.5f) * CVS0 + CR0);
    f[9] = zc - ((cc1 + 0.5f) * CVS1 + CR1);
    f[10] = x - bmx; f[11] = y - bmy;
    f[12] = ph - cmp; f[13] = zc - cmz;
    f[14] = sqrtf(x * x + y * y + z * z);
    f[15] = inten;
    for (int c = 0; c < 64; c++) {
        float a = 0.f;
        const float4* wr = (const float4*)&w1s[c * 16];
#pragma unroll
        for (int k4 = 0; k4 < 4; k4++) {
            float4 w = wr[k4];
            a = fmaf(f[4 * k4 + 0], w.x, a);
            a = fmaf(f[4 * k4 + 1], w.y, a);
            a = fmaf(f[4 * k4 + 2], w.z, a);
            a = fmaf(f[4 * k4 + 3], w.w, a);
        }
        h1[(long)c * N + p] = a;
    }
}

// ---- column sum/sumsq for column-major (C x N) buffer ----
__global__ void k_stats_cm(const float* __restrict__ buf, int N, float* __restrict__ out) {
    int c = blockIdx.y;
    int C = gridDim.y;
    const float* row = buf + (long)c * N;
    float s = 0.f, q = 0.f;
    for (int i = blockIdx.x * blockDim.x + threadIdx.x; i < N; i += gridDim.x * blockDim.x) {
        float v = row[i];
        s += v;
        q = fmaf(v, v, q);
    }
    __shared__ float ls[256], lq[256];
    ls[threadIdx.x] = s; lq[threadIdx.x] = q;
    __syncthreads();
    for (int k = 128; k > 0; k >>= 1) {
        if (threadIdx.x < k) { ls[threadIdx.x] += ls[threadIdx.x + k]; lq[threadIdx.x] += lq[threadIdx.x + k]; }
        __syncthreads();
    }
    if (threadIdx.x == 0) {
        atomicAdd(&out[c], ls[0]);
        atomicAdd(&out[C + c], lq[0]);
    }
}

// ---- sum/sumsq for channel-last buffer (total T elems, 64 channels) ----
__global__ void k_stats_cl(const float* __restrict__ buf, long T, float* __restrict__ out) {
    int t = threadIdx.x;
    int c = t & 63;
    float s = 0.f, q = 0.f;
    for (long i = (long)blockIdx.x * blockDim.x + t; i < T; i += (long)gridDim.x * blockDim.x) {
        float v = buf[i];
        s += v;
        q = fmaf(v, v, q);
    }
    __shared__ float ls[256], lq[256];
    ls[t] = s; lq[t] = q;
    __syncthreads();
    if (t < 64) {
        s = ls[t] + ls[t + 64] + ls[t + 128] + ls[t + 192];
        q = lq[t] + lq[t + 64] + lq[t + 128] + lq[t + 192];
        atomicAdd(&out[c], s);
        atomicAdd(&out[64 + c], q);
    }
}

// ---- BN finalize: st(sum,sq) + gamma,beta -> a,b with y = a*x + b ----
__global__ void k_finalize(const float* __restrict__ st, const float* __restrict__ g,
                           const float* __restrict__ b, float* __restrict__ ab, int C, float invn) {
    int c = blockIdx.x * blockDim.x + threadIdx.x;
    if (c >= C) return;
    float m = st[c] * invn;
    float v = st[C + c] * invn - m * m;
    float a = g[c] * rsqrtf(v + BN_EPS);
    ab[c] = a;
    ab[C + c] = b[c] - m * a;
}

// ---- GEMM2: BNReLU(h1) @ w2.T -> h2 column-major (128 x N) ----
__global__ void k_gemm2(const float* __restrict__ h1, const float* __restrict__ w2,
                        const float* __restrict__ ab1, float* __restrict__ h2, int N) {
    __shared__ float w2s[128 * 64];
    __shared__ float ab1s[128];
    int t = threadIdx.x;
    for (int i = t; i < 8192; i += blockDim.x) w2s[i] = w2[i];
    if (t < 128) ab1s[t] = ab1[t];
    __syncthreads();
    int p = blockIdx.x * blockDim.x + t;
    if (p >= N) return;
    float in[64];
#pragma unroll
    for (int c = 0; c < 64; c++) {
        in[c] = bnr(h1[(long)c * N + p], ab1s[c], ab1s[64 + c]);
    }
    for (int o = 0; o < 128; o++) {
        float a = 0.f;
        const float4* wr = (const float4*)&w2s[o * 64];
#pragma unroll
        for (int k4 = 0; k4 < 16; k4++) {
            float4 w = wr[k4];
            a = fmaf(in[4 * k4 + 0], w.x, a);
            a = fmaf(in[4 * k4 + 1], w.y, a);
            a = fmaf(in[4 * k4 + 2], w.z, a);
            a = fmaf(in[4 * k4 + 3], w.w, a);
        }
        h2[(long)o * N + p] = a;
    }
}

// ---- scatter BNReLU(h2[:,:64]) max into dense cyl grid (B,512,48,64), uint-bits ----
__global__ void k_cylmax(const float* __restrict__ h2, const float* __restrict__ ab2,
                         const float* __restrict__ pts, const float* __restrict__ cylidx,
                         unsigned int* __restrict__ grid, int N) {
    int p = blockIdx.x * blockDim.x + threadIdx.x;
    if (p >= N) return;
    int b = (int)pts[p * 5 + 0];
    int cx = (int)floorf(cylidx[p * 2 + 0]);
    int cy = (int)floorf(cylidx[p * 2 + 1]);
    unsigned int* cell = grid + (((long)b * 512 + cx) * 48 + cy) * 64;
    for (int c = 0; c < 64; c++) {
        float v = bnr(h2[(long)c * N + p], ab2[c], ab2[128 + c]);
        atomicMax(&cell[c], __float_as_uint(v));
    }
}

// ---- 3x3 SAME conv, NHWC (B,512,48,64) -> same, 64->64 channels ----
__global__ __launch_bounds__(256) void k_conv(const float* __restrict__ gridin,
                                              const float* __restrict__ wct,
                                              float* __restrict__ out) {
    __shared__ float in_s[64 * 65];
    __shared__ float w_s[64 * 64];
    int t = threadIdx.x;
    int bid = blockIdx.x;
    int b = bid / (64 * 6);
    int r = bid % (64 * 6);
    int h0 = (r / 6) * 8, w0 = (r % 6) * 8;
    float acc[4][4];
#pragma unroll
    for (int i = 0; i < 4; i++)
#pragma unroll
        for (int j = 0; j < 4; j++) acc[i][j] = 0.f;
    int tp = t & 15, to = t >> 4;
    for (int tap = 0; tap < 9; tap++) {
        int dh = tap / 3 - 1, dw = tap % 3 - 1;
        __syncthreads();
#pragma unroll
        for (int i = 0; i < 16; i++) w_s[t + i * 256] = wct[tap * 4096 + t + i * 256];
#pragma unroll
        for (int i = 0; i < 4; i++) {
            int flat = t + i * 256;
            int pix = flat >> 4, c4 = flat & 15;
            int ph = pix >> 3, pw = pix & 7;
            int hh = h0 + ph + dh, ww = w0 + pw + dw;
            float4 v = make_float4(0.f, 0.f, 0.f, 0.f);
            if (hh >= 0 && hh < 512 && ww >= 0 && ww < 48)
                v = *(const float4*)&gridin[(((long)b * 512 + hh) * 48 + ww) * 64 + c4 * 4];
            in_s[pix * 65 + c4 * 4 + 0] = v.x;
            in_s[pix * 65 + c4 * 4 + 1] = v.y;
            in_s[pix * 65 + c4 * 4 + 2] = v.z;
            in_s[pix * 65 + c4 * 4 + 3] = v.w;
        }
        __syncthreads();
#pragma unroll 4
        for (int ic = 0; ic < 64; ic++) {
            float i0 = in_s[(tp * 4 + 0) * 65 + ic];
            float i1 = in_s[(tp * 4 + 1) * 65 + ic];
            float i2 = in_s[(tp * 4 + 2) * 65 + ic];
            float i3 = in_s[(tp * 4 + 3) * 65 + ic];
            float4 w = *(const float4*)&w_s[ic * 64 + to * 4];
            acc[0][0] = fmaf(i0, w.x, acc[0][0]); acc[0][1] = fmaf(i0, w.y, acc[0][1]);
            acc[0][2] = fmaf(i0, w.z, acc[0][2]); acc[0][3] = fmaf(i0, w.w, acc[0][3]);
            acc[1][0] = fmaf(i1, w.x, acc[1][0]); acc[1][1] = fmaf(i1, w.y, acc[1][1]);
            acc[1][2] = fmaf(i1, w.z, acc[1][2]); acc[1][3] = fmaf(i1, w.w, acc[1][3]);
            acc[2][0] = fmaf(i2, w.x, acc[2][0]); acc[2][1] = fmaf(i2, w.y, acc[2][1]);
            acc[2][2] = fmaf(i2, w.z, acc[2][2]); acc[2][3] = fmaf(i2, w.w, acc[2][3]);
            acc[3][0] = fmaf(i3, w.x, acc[3][0]); acc[3][1] = fmaf(i3, w.y, acc[3][1]);
            acc[3][2] = fmaf(i3, w.z, acc[3][2]); acc[3][3] = fmaf(i3, w.w, acc[3][3]);
        }
    }
#pragma unroll
    for (int i = 0; i < 4; i++) {
        int pix = tp * 4 + i;
        int ph = pix >> 3, pw = pix & 7;
        float4 v = make_float4(acc[i][0], acc[i][1], acc[i][2], acc[i][3]);
        *(float4*)&out[(((long)b * 512 + h0 + ph) * 48 + w0 + pw) * 64 + to * 4] = v;
    }
}

// ---- bilinear gather (with conv BN-ReLU on the fly) + GEMM3 -> h3 column-major (64 x N) ----
__global__ void k_gather_gemm3(const float* __restrict__ h2, const float* __restrict__ conv,
                               const float* __restrict__ ab2, const float* __restrict__ abC,
                               const float* __restrict__ cylidx, const float* __restrict__ pts,
                               const float* __restrict__ w3, float* __restrict__ h3, int N) {
    __shared__ float w3s[64 * 128];
    __shared__ float ab2s[256];
    __shared__ float abCs[128];
    int t = threadIdx.x;
    for (int i = t; i < 8192; i += 256) w3s[i] = w3[i];
    if (t < 256) ab2s[t] = ab2[t];
    if (t < 128) abCs[t] = abC[t];
    __syncthreads();
    int p = blockIdx.x * 256 + t;
    if (p >= N) return;
    float yq = cylidx[p * 2 + 0], xq = cylidx[p * 2 + 1];
    int b = (int)pts[p * 5 + 0];
    int xf = (int)floorf(xq), yf = (int)floorf(yq);
    int x0 = min(max(xf, 0), 47);
    int x1 = min(max(xf + 1, 0), 47);
    int y0 = min(max(yf, 0), 511);
    int y1 = min(max(yf + 1, 0), 511);
    float x0f = (float)x0, x1f = (float)x1, y0f = (float)y0, y1f = (float)y1;
    float wa = (x1f - xq) * (y1f - yq);
    float wb = (x1f - xq) * (yq - y0f);
    float wc = (xq - x0f) * (y1f - yq);
    float wd = (xq - x0f) * (yq - y0f);
    const float* Ia = conv + (((long)b * 512 + y0) * 48 + x0) * 64;
    const float* Ib = conv + (((long)b * 512 + y1) * 48 + x0) * 64;
    const float* Ic = conv + (((long)b * 512 + y0) * 48 + x1) * 64;
    const float* Id = conv + (((long)b * 512 + y1) * 48 + x1) * 64;
    float acc[64];
#pragma unroll
    for (int o = 0; o < 64; o++) acc[o] = 0.f;
    // k = 0..63 : pointwise = BNReLU(h2[64..128])
    for (int kb = 0; kb < 4; kb++) {
        float in16[16];
#pragma unroll
        for (int k = 0; k < 16; k++) {
            int c = kb * 16 + k;
            in16[k] = bnr(h2[(long)(64 + c) * N + p], ab2s[64 + c], ab2s[192 + c]);
        }
        for (int o = 0; o < 64; o++) {
            float a = acc[o];
            const float4* wr = (const float4*)&w3s[o * 128 + kb * 16];
#pragma unroll
            for (int k4 = 0; k4 < 4; k4++) {
                float4 w = wr[k4];
                a = fmaf(in16[4 * k4 + 0], w.x, a);
                a = fmaf(in16[4 * k4 + 1], w.y, a);
                a = fmaf(in16[4 * k4 + 2], w.z, a);
                a = fmaf(in16[4 * k4 + 3], w.w, a);
            }
            acc[o] = a;
        }
    }
    // k = 64..127 : bilinear-sampled conv features
    for (int kb = 0; kb < 4; kb++) {
        float in16[16];
#pragma unroll
        for (int k = 0; k < 16; k++) {
            int c = kb * 16 + k;
            float aC = abCs[c], bC = abCs[64 + c];
            float va = bnr(Ia[c], aC, bC);
            float vb2 = bnr(Ib[c], aC, bC);
            float vc2 = bnr(Ic[c], aC, bC);
            float vd = bnr(Id[c], aC, bC);
            in16[k] = wa * va + wb * vb2 + wc * vc2 + wd * vd;
        }
        for (int o = 0; o < 64; o++) {
            float a = acc[o];
            const float4* wr = (const float4*)&w3s[o * 128 + 64 + kb * 16];
#pragma unroll
            for (int k4 = 0; k4 < 4; k4++) {
                float4 w = wr[k4];
                a = fmaf(in16[4 * k4 + 0], w.x, a);
                a = fmaf(in16[4 * k4 + 1], w.y, a);
                a = fmaf(in16[4 * k4 + 2], w.z, a);
                a = fmaf(in16[4 * k4 + 3], w.w, a);
            }
            acc[o] = a;
        }
    }
    for (int o = 0; o < 64; o++) h3[(long)o * N + p] = acc[o];
}

// ---- final BN-ReLU, transpose to row-major out, scatter-max into bev ----
__global__ void k_out_tile(const float* __restrict__ h3, const float* __restrict__ ab3,
                           const int* __restrict__ binv, float* __restrict__ out_fea,
                           unsigned int* __restrict__ out_bev, int N) {
    __shared__ float tile[64 * 65];
    int t = threadIdx.x;
    int p0 = blockIdx.x * 64;
    {
        int pl = t & 63;
        int cg = t >> 6;
#pragma unroll
        for (int i = 0; i < 16; i++) {
            int c = i * 4 + cg;
            int p = p0 + pl;
            float v = 0.f;
            if (p < N) v = h3[(long)c * N + p];
            v = fmaxf(fmaf(v, ab3[c], ab3[64 + c]), 0.f);
            tile[c * 65 + pl] = v;
        }
    }
    __syncthreads();
    {
        int c = t & 63;
        int pg = t >> 6;
#pragma unroll
        for (int i = 0; i < 16; i++) {
            int pl2 = i * 4 + pg;
            int p = p0 + pl2;
            if (p < N) {
                float v = tile[c * 65 + pl2];
                out_fea[(long)p * 64 + c] = v;
                int bi = binv[p];
                atomicMax(&out_bev[(long)bi * 64 + c], __float_as_uint(v));
            }
        }
    }
}

// ---- voxel coords (written as float; integers are exact in fp32) ----
__global__ void k_voxcoords(const int* __restrict__ coords, float* __restrict__ out, int Nb) {
    int i = blockIdx.x * blockDim.x + threadIdx.x;
    if (i >= Nb) return;
    int c = coords[i];
    int vb = c / BEV_SXY;
    int rem = c % BEV_SXY;
    int vx = rem / BEV_SY;
    int vy = rem % BEV_SY;
    out[i * 4 + 0] = (float)vb;
    out[i * 4 + 1] = 0.f;
    out[i * 4 + 2] = (float)vy;
    out[i * 4 + 3] = (float)vx;
}

extern "C" void kernel_launch(void* const* d_in, const int* in_sizes, int n_in,
                              void* d_out, int out_size, void* d_ws, size_t ws_size,
                              hipStream_t stream) {
    const float* pts = (const float*)d_in[0];
    const float* pcyl = (const float*)d_in[1];
    const float* cylidx = (const float*)d_in[2];
    const float* bevidx = (const float*)d_in[3];
    const float* w1 = (const float*)d_in[4];
    const float* g1 = (const float*)d_in[5];
    const float* b1 = (const float*)d_in[6];
    const float* w2 = (const float*)d_in[7];
    const float* g2 = (const float*)d_in[8];
    const float* b2 = (const float*)d_in[9];
    const float* wc = (const float*)d_in[10];
    const float* gc = (const float*)d_in[11];
    const float* bc = (const float*)d_in[12];
    const float* w3 = (const float*)d_in[13];
    const float* g3 = (const float*)d_in[14];
    const float* b3 = (const float*)d_in[15];
    const int* binv = (const int*)d_in[16];
    const int* bcoords = (const int*)d_in[17];
    const int* cinv = (const int*)d_in[18];
    const int* ccoords = (const int*)d_in[19];
    int N = in_sizes[0] / 5;
    int Nb = in_sizes[17];
    int Nc = in_sizes[19];
    const int B = 4;
    const long GRIDSZ = (long)B * 512 * 48 * 64;

    float* ws = (float*)d_ws;
    long off = 0;
    float* h2 = ws + off;   off += (long)128 * N;
    float* h13 = ws + off;  off += (long)64 * N;   // h1, later reused as h3
    float* grid = ws + off; off += GRIDSZ;
    float* conv = ws + off; off += GRIDSZ;
    float* bacc = ws + off; off += 3L * Nb;
    float* cacc = ws + off; off += 3L * Nc;
    float* stats = ws + off; off += 1280;
    float* wct = ws + off;  off += 9 * 64 * 64;
    float* st1 = stats, *st2 = stats + 128, *st3 = stats + 384, *stC = stats + 512;
    float* ab1 = stats + 640, *ab2 = stats + 768, *ab3 = stats + 1024, *abC = stats + 1152;

    float* out_fea = (float*)d_out;
    unsigned int* out_bev = (unsigned int*)((float*)d_out + (long)N * 64);
    float* out_vc = (float*)d_out + (long)N * 64 + (long)Nb * 64;

    hipMemsetAsync(grid, 0, (size_t)GRIDSZ * 4, stream);
    hipMemsetAsync(bacc, 0, (size_t)3 * Nb * 4, stream);
    hipMemsetAsync(cacc, 0, (size_t)3 * Nc * 4, stream);
    hipMemsetAsync(stats, 0, 1280 * 4, stream);
    hipMemsetAsync(out_bev, 0, (size_t)Nb * 64 * 4, stream);

    int nb256 = (N + 255) / 256;
    k_wct<<<(9 * 64 * 64 + 255) / 256, 256, 0, stream>>>(wc, wct);
    k_scatter_sums<<<nb256, 256, 0, stream>>>(pts, pcyl, binv, cinv, bacc, cacc, N, Nb, Nc);
    k_feat_gemm1<<<nb256, 256, 0, stream>>>(pts, pcyl, cylidx, bevidx, binv, cinv, bacc, cacc, w1, h13, N, Nb, Nc);
    {
        dim3 g(32, 64);
        k_stats_cm<<<g, 256, 0, stream>>>(h13, N, st1);
    }
    k_finalize<<<1, 128, 0, stream>>>(st1, g1, b1, ab1, 64, 1.0f / (float)N);
    k_gemm2<<<nb256, 256, 0, stream>>>(h13, w2, ab1, h2, N);
    {
        dim3 g(32, 128);
        k_stats_cm<<<g, 256, 0, stream>>>(h2, N, st2);
    }
    k_finalize<<<1, 128, 0, stream>>>(st2, g2, b2, ab2, 128, 1.0f / (float)N);
    k_cylmax<<<nb256, 256, 0, stream>>>(h2, ab2, pts, cylidx, (unsigned int*)grid, N);
    k_conv<<<B * 64 * 6, 256, 0, stream>>>(grid, wct, conv);
    k_stats_cl<<<512, 256, 0, stream>>>(conv, GRIDSZ, stC);
    k_finalize<<<1, 128, 0, stream>>>(stC, gc, bc, abC, 64, 1.0f / (float)(B * 512 * 48));
    k_gather_gemm3<<<nb256, 256, 0, stream>>>(h2, conv, ab2, abC, cylidx, pts, w3, h13, N);
    {
        dim3 g(32, 64);
        k_stats_cm<<<g, 256, 0, stream>>>(h13, N, st3);
    }
    k_finalize<<<1, 128, 0, stream>>>(st3, g3, b3, ab3, 64, 1.0f / (float)N);
    k_out_tile<<<(N + 63) / 64, 256, 0, stream>>>(h13, ab3, binv, out_fea, out_bev, N);
    k_voxcoords<<<(Nb + 255) / 256, 256, 0, stream>>>(bcoords, out_vc, Nb);
}

// Round 2
// 1064.949 us; speedup vs baseline: 1.5111x; 1.5111x over previous
//
#include <hip/hip_runtime.h>
#include <math.h>

#define BN_EPS 1e-3f

// cyl/bev constants (match reference; computed in double, cast to f32 like jnp would)
static constexpr float CR0 = -3.14159265f;
static constexpr float CR1 = -2.0f;
static constexpr float CVS0 = (float)((3.14159265 * 2.0) / 512.0);
static constexpr float CVS1 = (float)(6.0 / 48.0);
#define BEV_SXY (220 * 250)
#define BEV_SY 250

__device__ __forceinline__ float bnr(float x, float a, float b) {
    float v = fmaf(x, a, b);
    return v > 0.f ? v : 0.f;
}

// ---- weight transpose for conv: wc[o][i][kh][kw] -> wct[(kh*3+kw)][i][o] ----
__global__ void k_wct(const float* __restrict__ wc, float* __restrict__ wct) {
    int tid = blockIdx.x * blockDim.x + threadIdx.x;
    if (tid >= 9 * 64 * 64) return;
    int tap = tid / 4096;
    int rem = tid % 4096;
    int i = rem / 64;
    int o = rem % 64;
    int kh = tap / 3, kw = tap % 3;
    wct[tid] = wc[((o * 64 + i) * 3 + kh) * 3 + kw];
}

// ---- segment sums for means (bev: cnt,x,y ; cyl: cnt,phi,z) ----
__global__ void k_scatter_sums(const float* __restrict__ pts, const float* __restrict__ pcyl,
                               const int* __restrict__ binv, const int* __restrict__ cinv,
                               float* __restrict__ bacc, float* __restrict__ cacc,
                               int N, int Nb, int Nc) {
    int p = blockIdx.x * blockDim.x + threadIdx.x;
    if (p >= N) return;
    float x = pts[p * 5 + 1], y = pts[p * 5 + 2];
    float ph = pcyl[p * 3 + 0], z = pcyl[p * 3 + 1];
    int bi = binv[p], ci = cinv[p];
    atomicAdd(&bacc[bi], 1.0f);
    atomicAdd(&bacc[Nb + bi], x);
    atomicAdd(&bacc[2 * Nb + bi], y);
    atomicAdd(&cacc[ci], 1.0f);
    atomicAdd(&cacc[Nc + ci], ph);
    atomicAdd(&cacc[2 * Nc + ci], z);
}

// ---- build 16-dim feature + GEMM1 (16->64), h1 stored column-major (64 x N) ----
__global__ void k_feat_gemm1(const float* __restrict__ pts, const float* __restrict__ pcyl,
                             const float* __restrict__ cylidx, const float* __restrict__ bevidx,
                             const int* __restrict__ binv, const int* __restrict__ cinv,
                             const float* __restrict__ bacc, const float* __restrict__ cacc,
                             const float* __restrict__ w1, float* __restrict__ h1,
                             int N, int Nb, int Nc) {
    __shared__ float w1s[64 * 16];
    int t = threadIdx.x;
    for (int i = t; i < 1024; i += blockDim.x) w1s[i] = w1[i];
    __syncthreads();
    int p = blockIdx.x * blockDim.x + t;
    if (p >= N) return;
    float x = pts[p * 5 + 1], y = pts[p * 5 + 2], z = pts[p * 5 + 3], inten = pts[p * 5 + 4];
    float ph = pcyl[p * 3 + 0], zc = pcyl[p * 3 + 1], rho = pcyl[p * 3 + 2];
    float ci0 = cylidx[p * 2 + 0], ci1 = cylidx[p * 2 + 1];
    float bi0 = bevidx[p * 2 + 0], bi1 = bevidx[p * 2 + 1];
    float bc0 = floorf(bi0), bc1 = floorf(bi1);
    float cc0 = floorf(ci0), cc1 = floorf(ci1);
    int bv = binv[p], cv = cinv[p];
    float bcnt = bacc[bv];
    float bmx = bacc[Nb + bv] / bcnt, bmy = bacc[2 * Nb + bv] / bcnt;
    float ccnt = cacc[cv];
    float cmp = cacc[Nc + cv] / ccnt, cmz = cacc[2 * Nc + cv] / ccnt;
    float f[16];
    f[0] = x; f[1] = y; f[2] = z;
    f[3] = ph; f[4] = zc; f[5] = rho;
    f[6] = x - ((bc0 + 0.5f) * 0.32f + 0.0f);
    f[7] = y - ((bc1 + 0.5f) * 0.32f + (-40.0f));
    f[8] = ph - ((cc0 + 0.5f) * CVS0 + CR0);
    f[9] = zc - ((cc1 + 0.5f) * CVS1 + CR1);
    f[10] = x - bmx; f[11] = y - bmy;
    f[12] = ph - cmp; f[13] = zc - cmz;
    f[14] = sqrtf(x * x + y * y + z * z);
    f[15] = inten;
    for (int c = 0; c < 64; c++) {
        float a = 0.f;
        const float4* wr = (const float4*)&w1s[c * 16];
#pragma unroll
        for (int k4 = 0; k4 < 4; k4++) {
            float4 w = wr[k4];
            a = fmaf(f[4 * k4 + 0], w.x, a);
            a = fmaf(f[4 * k4 + 1], w.y, a);
            a = fmaf(f[4 * k4 + 2], w.z, a);
            a = fmaf(f[4 * k4 + 3], w.w, a);
        }
        h1[(long)c * N + p] = a;
    }
}

// ---- column sum/sumsq for column-major (C x N) buffer ----
__global__ void k_stats_cm(const float* __restrict__ buf, int N, float* __restrict__ out) {
    int c = blockIdx.y;
    int C = gridDim.y;
    const float* row = buf + (long)c * N;
    float s = 0.f, q = 0.f;
    for (int i = blockIdx.x * blockDim.x + threadIdx.x; i < N; i += gridDim.x * blockDim.x) {
        float v = row[i];
        s += v;
        q = fmaf(v, v, q);
    }
    __shared__ float ls[256], lq[256];
    ls[threadIdx.x] = s; lq[threadIdx.x] = q;
    __syncthreads();
    for (int k = 128; k > 0; k >>= 1) {
        if (threadIdx.x < k) { ls[threadIdx.x] += ls[threadIdx.x + k]; lq[threadIdx.x] += lq[threadIdx.x + k]; }
        __syncthreads();
    }
    if (threadIdx.x == 0) {
        atomicAdd(&out[c], ls[0]);
        atomicAdd(&out[C + c], lq[0]);
    }
}

// ---- sum/sumsq for channel-last buffer (total T elems, 64 channels) ----
__global__ void k_stats_cl(const float* __restrict__ buf, long T, float* __restrict__ out) {
    int t = threadIdx.x;
    int c = t & 63;
    float s = 0.f, q = 0.f;
    for (long i = (long)blockIdx.x * blockDim.x + t; i < T; i += (long)gridDim.x * blockDim.x) {
        float v = buf[i];
        s += v;
        q = fmaf(v, v, q);
    }
    __shared__ float ls[256], lq[256];
    ls[t] = s; lq[t] = q;
    __syncthreads();
    if (t < 64) {
        s = ls[t] + ls[t + 64] + ls[t + 128] + ls[t + 192];
        q = lq[t] + lq[t + 64] + lq[t + 128] + lq[t + 192];
        atomicAdd(&out[c], s);
        atomicAdd(&out[64 + c], q);
    }
}

// ---- BN finalize: st(sum,sq) + gamma,beta -> a,b with y = a*x + b ----
__global__ void k_finalize(const float* __restrict__ st, const float* __restrict__ g,
                           const float* __restrict__ b, float* __restrict__ ab, int C, float invn) {
    int c = blockIdx.x * blockDim.x + threadIdx.x;
    if (c >= C) return;
    float m = st[c] * invn;
    float v = st[C + c] * invn - m * m;
    float a = g[c] * rsqrtf(v + BN_EPS);
    ab[c] = a;
    ab[C + c] = b[c] - m * a;
}

// ---- GEMM2: BNReLU(h1) @ w2.T -> h2 column-major (128 x N) ----
__global__ void k_gemm2(const float* __restrict__ h1, const float* __restrict__ w2,
                        const float* __restrict__ ab1, float* __restrict__ h2, int N) {
    __shared__ float w2s[128 * 64];
    __shared__ float ab1s[128];
    int t = threadIdx.x;
    for (int i = t; i < 8192; i += blockDim.x) w2s[i] = w2[i];
    if (t < 128) ab1s[t] = ab1[t];
    __syncthreads();
    int p = blockIdx.x * blockDim.x + t;
    if (p >= N) return;
    float in[64];
#pragma unroll
    for (int c = 0; c < 64; c++) {
        in[c] = bnr(h1[(long)c * N + p], ab1s[c], ab1s[64 + c]);
    }
    for (int o = 0; o < 128; o++) {
        float a = 0.f;
        const float4* wr = (const float4*)&w2s[o * 64];
#pragma unroll
        for (int k4 = 0; k4 < 16; k4++) {
            float4 w = wr[k4];
            a = fmaf(in[4 * k4 + 0], w.x, a);
            a = fmaf(in[4 * k4 + 1], w.y, a);
            a = fmaf(in[4 * k4 + 2], w.z, a);
            a = fmaf(in[4 * k4 + 3], w.w, a);
        }
        h2[(long)o * N + p] = a;
    }
}

// ---- scatter BNReLU(h2[:,:64]) max into dense cyl grid (B,512,48,64) ----
// LDS-transposed: each wave handles one point's 64 channels -> coalesced cell
// access; zero-skip + read-check make most atomics unnecessary (grid 0-init,
// values >= 0, max is monotone so a stale-low read only costs an extra atomic).
__global__ __launch_bounds__(256) void k_cylmax2(const float* __restrict__ h2,
                                                 const float* __restrict__ ab2,
                                                 const float* __restrict__ pts,
                                                 const float* __restrict__ cylidx,
                                                 unsigned int* __restrict__ grid, int N) {
    __shared__ float tile[64 * 65];
    __shared__ float ab2s[256];
    int t = threadIdx.x;
    ab2s[t] = ab2[t];
    __syncthreads();
    int p0 = blockIdx.x * 64;
    int lane = t & 63, grp = t >> 6;
#pragma unroll
    for (int i = 0; i < 16; i++) {
        int c = i * 4 + grp;              // uniform per wave
        int p = p0 + lane;
        float v = (p < N) ? h2[(long)c * N + p] : 0.f;   // coalesced
        tile[c * 65 + lane] = bnr(v, ab2s[c], ab2s[128 + c]);
    }
    __syncthreads();
    // each of the 4 waves handles 16 points; lane = channel
    for (int j = 0; j < 16; j++) {
        int pl = grp * 16 + j;
        int p = p0 + pl;
        if (p >= N) break;                // wave-uniform
        int b = (int)pts[p * 5 + 0];      // broadcast loads (p uniform per wave)
        int cx = (int)floorf(cylidx[p * 2 + 0]);
        int cy = (int)floorf(cylidx[p * 2 + 1]);
        unsigned int* cell = grid + (((long)b * 512 + cx) * 48 + cy) * 64;
        float v = tile[lane * 65 + pl];   // bank-conflict-free (2-way, free)
        if (v > 0.f) {
            unsigned int uv = __float_as_uint(v);
            unsigned int cur = cell[lane];        // coalesced 256B read, L2-hot
            if (uv > cur) atomicMax(&cell[lane], uv);
        }
    }
}

// ---- 3x3 SAME conv, NHWC (B,512,48,64) -> same, 64->64 channels ----
__global__ __launch_bounds__(256) void k_conv(const float* __restrict__ gridin,
                                              const float* __restrict__ wct,
                                              float* __restrict__ out) {
    __shared__ float in_s[64 * 65];
    __shared__ float w_s[64 * 64];
    int t = threadIdx.x;
    int bid = blockIdx.x;
    int b = bid / (64 * 6);
    int r = bid % (64 * 6);
    int h0 = (r / 6) * 8, w0 = (r % 6) * 8;
    float acc[4][4];
#pragma unroll
    for (int i = 0; i < 4; i++)
#pragma unroll
        for (int j = 0; j < 4; j++) acc[i][j] = 0.f;
    int tp = t & 15, to = t >> 4;
    for (int tap = 0; tap < 9; tap++) {
        int dh = tap / 3 - 1, dw = tap % 3 - 1;
        __syncthreads();
#pragma unroll
        for (int i = 0; i < 16; i++) w_s[t + i * 256] = wct[tap * 4096 + t + i * 256];
#pragma unroll
        for (int i = 0; i < 4; i++) {
            int flat = t + i * 256;
            int pix = flat >> 4, c4 = flat & 15;
            int ph = pix >> 3, pw = pix & 7;
            int hh = h0 + ph + dh, ww = w0 + pw + dw;
            float4 v = make_float4(0.f, 0.f, 0.f, 0.f);
            if (hh >= 0 && hh < 512 && ww >= 0 && ww < 48)
                v = *(const float4*)&gridin[(((long)b * 512 + hh) * 48 + ww) * 64 + c4 * 4];
            in_s[pix * 65 + c4 * 4 + 0] = v.x;
            in_s[pix * 65 + c4 * 4 + 1] = v.y;
            in_s[pix * 65 + c4 * 4 + 2] = v.z;
            in_s[pix * 65 + c4 * 4 + 3] = v.w;
        }
        __syncthreads();
#pragma unroll 4
        for (int ic = 0; ic < 64; ic++) {
            float i0 = in_s[(tp * 4 + 0) * 65 + ic];
            float i1 = in_s[(tp * 4 + 1) * 65 + ic];
            float i2 = in_s[(tp * 4 + 2) * 65 + ic];
            float i3 = in_s[(tp * 4 + 3) * 65 + ic];
            float4 w = *(const float4*)&w_s[ic * 64 + to * 4];
            acc[0][0] = fmaf(i0, w.x, acc[0][0]); acc[0][1] = fmaf(i0, w.y, acc[0][1]);
            acc[0][2] = fmaf(i0, w.z, acc[0][2]); acc[0][3] = fmaf(i0, w.w, acc[0][3]);
            acc[1][0] = fmaf(i1, w.x, acc[1][0]); acc[1][1] = fmaf(i1, w.y, acc[1][1]);
            acc[1][2] = fmaf(i1, w.z, acc[1][2]); acc[1][3] = fmaf(i1, w.w, acc[1][3]);
            acc[2][0] = fmaf(i2, w.x, acc[2][0]); acc[2][1] = fmaf(i2, w.y, acc[2][1]);
            acc[2][2] = fmaf(i2, w.z, acc[2][2]); acc[2][3] = fmaf(i2, w.w, acc[2][3]);
            acc[3][0] = fmaf(i3, w.x, acc[3][0]); acc[3][1] = fmaf(i3, w.y, acc[3][1]);
            acc[3][2] = fmaf(i3, w.z, acc[3][2]); acc[3][3] = fmaf(i3, w.w, acc[3][3]);
        }
    }
#pragma unroll
    for (int i = 0; i < 4; i++) {
        int pix = tp * 4 + i;
        int ph = pix >> 3, pw = pix & 7;
        float4 v = make_float4(acc[i][0], acc[i][1], acc[i][2], acc[i][3]);
        *(float4*)&out[(((long)b * 512 + h0 + ph) * 48 + w0 + pw) * 64 + to * 4] = v;
    }
}

// ---- bilinear gather (with conv BN-ReLU on the fly) + GEMM3 -> h3 column-major (64 x N) ----
__global__ void k_gather_gemm3(const float* __restrict__ h2, const float* __restrict__ conv,
                               const float* __restrict__ ab2, const float* __restrict__ abC,
                               const float* __restrict__ cylidx, const float* __restrict__ pts,
                               const float* __restrict__ w3, float* __restrict__ h3, int N) {
    __shared__ float w3s[64 * 128];
    __shared__ float ab2s[256];
    __shared__ float abCs[128];
    int t = threadIdx.x;
    for (int i = t; i < 8192; i += 256) w3s[i] = w3[i];
    if (t < 256) ab2s[t] = ab2[t];
    if (t < 128) abCs[t] = abC[t];
    __syncthreads();
    int p = blockIdx.x * 256 + t;
    if (p >= N) return;
    float yq = cylidx[p * 2 + 0], xq = cylidx[p * 2 + 1];
    int b = (int)pts[p * 5 + 0];
    int xf = (int)floorf(xq), yf = (int)floorf(yq);
    int x0 = min(max(xf, 0), 47);
    int x1 = min(max(xf + 1, 0), 47);
    int y0 = min(max(yf, 0), 511);
    int y1 = min(max(yf + 1, 0), 511);
    float x0f = (float)x0, x1f = (float)x1, y0f = (float)y0, y1f = (float)y1;
    float wa = (x1f - xq) * (y1f - yq);
    float wb = (x1f - xq) * (yq - y0f);
    float wc = (xq - x0f) * (y1f - yq);
    float wd = (xq - x0f) * (yq - y0f);
    const float* Ia = conv + (((long)b * 512 + y0) * 48 + x0) * 64;
    const float* Ib = conv + (((long)b * 512 + y1) * 48 + x0) * 64;
    const float* Ic = conv + (((long)b * 512 + y0) * 48 + x1) * 64;
    const float* Id = conv + (((long)b * 512 + y1) * 48 + x1) * 64;
    float acc[64];
#pragma unroll
    for (int o = 0; o < 64; o++) acc[o] = 0.f;
    // k = 0..63 : pointwise = BNReLU(h2[64..128])
    for (int kb = 0; kb < 4; kb++) {
        float in16[16];
#pragma unroll
        for (int k = 0; k < 16; k++) {
            int c = kb * 16 + k;
            in16[k] = bnr(h2[(long)(64 + c) * N + p], ab2s[64 + c], ab2s[192 + c]);
        }
        for (int o = 0; o < 64; o++) {
            float a = acc[o];
            const float4* wr = (const float4*)&w3s[o * 128 + kb * 16];
#pragma unroll
            for (int k4 = 0; k4 < 4; k4++) {
                float4 w = wr[k4];
                a = fmaf(in16[4 * k4 + 0], w.x, a);
                a = fmaf(in16[4 * k4 + 1], w.y, a);
                a = fmaf(in16[4 * k4 + 2], w.z, a);
                a = fmaf(in16[4 * k4 + 3], w.w, a);
            }
            acc[o] = a;
        }
    }
    // k = 64..127 : bilinear-sampled conv features
    for (int kb = 0; kb < 4; kb++) {
        float in16[16];
#pragma unroll
        for (int k = 0; k < 16; k++) {
            int c = kb * 16 + k;
            float aC = abCs[c], bC = abCs[64 + c];
            float va = bnr(Ia[c], aC, bC);
            float vb2 = bnr(Ib[c], aC, bC);
            float vc2 = bnr(Ic[c], aC, bC);
            float vd = bnr(Id[c], aC, bC);
            in16[k] = wa * va + wb * vb2 + wc * vc2 + wd * vd;
        }
        for (int o = 0; o < 64; o++) {
            float a = acc[o];
            const float4* wr = (const float4*)&w3s[o * 128 + 64 + kb * 16];
#pragma unroll
            for (int k4 = 0; k4 < 4; k4++) {
                float4 w = wr[k4];
                a = fmaf(in16[4 * k4 + 0], w.x, a);
                a = fmaf(in16[4 * k4 + 1], w.y, a);
                a = fmaf(in16[4 * k4 + 2], w.z, a);
                a = fmaf(in16[4 * k4 + 3], w.w, a);
            }
            acc[o] = a;
        }
    }
    for (int o = 0; o < 64; o++) h3[(long)o * N + p] = acc[o];
}

// ---- final BN-ReLU, transpose to row-major out, scatter-max into bev ----
__global__ void k_out_tile(const float* __restrict__ h3, const float* __restrict__ ab3,
                           const int* __restrict__ binv, float* __restrict__ out_fea,
                           unsigned int* __restrict__ out_bev, int N) {
    __shared__ float tile[64 * 65];
    int t = threadIdx.x;
    int p0 = blockIdx.x * 64;
    {
        int pl = t & 63;
        int cg = t >> 6;
#pragma unroll
        for (int i = 0; i < 16; i++) {
            int c = i * 4 + cg;
            int p = p0 + pl;
            float v = 0.f;
            if (p < N) v = h3[(long)c * N + p];
            v = fmaxf(fmaf(v, ab3[c], ab3[64 + c]), 0.f);
            tile[c * 65 + pl] = v;
        }
    }
    __syncthreads();
    {
        int c = t & 63;
        int pg = t >> 6;
#pragma unroll
        for (int i = 0; i < 16; i++) {
            int pl2 = i * 4 + pg;
            int p = p0 + pl2;
            if (p < N) {
                float v = tile[c * 65 + pl2];
                out_fea[(long)p * 64 + c] = v;
                int bi = binv[p];    // broadcast (p uniform per wave)
                if (v > 0.f) {
                    unsigned int uv = __float_as_uint(v);
                    unsigned int cur = out_bev[(long)bi * 64 + c];  // coalesced
                    if (uv > cur) atomicMax(&out_bev[(long)bi * 64 + c], uv);
                }
            }
        }
    }
}

// ---- voxel coords (written as float; integers are exact in fp32) ----
__global__ void k_voxcoords(const int* __restrict__ coords, float* __restrict__ out, int Nb) {
    int i = blockIdx.x * blockDim.x + threadIdx.x;
    if (i >= Nb) return;
    int c = coords[i];
    int vb = c / BEV_SXY;
    int rem = c % BEV_SXY;
    int vx = rem / BEV_SY;
    int vy = rem % BEV_SY;
    out[i * 4 + 0] = (float)vb;
    out[i * 4 + 1] = 0.f;
    out[i * 4 + 2] = (float)vy;
    out[i * 4 + 3] = (float)vx;
}

extern "C" void kernel_launch(void* const* d_in, const int* in_sizes, int n_in,
                              void* d_out, int out_size, void* d_ws, size_t ws_size,
                              hipStream_t stream) {
    const float* pts = (const float*)d_in[0];
    const float* pcyl = (const float*)d_in[1];
    const float* cylidx = (const float*)d_in[2];
    const float* bevidx = (const float*)d_in[3];
    const float* w1 = (const float*)d_in[4];
    const float* g1 = (const float*)d_in[5];
    const float* b1 = (const float*)d_in[6];
    const float* w2 = (const float*)d_in[7];
    const float* g2 = (const float*)d_in[8];
    const float* b2 = (const float*)d_in[9];
    const float* wc = (const float*)d_in[10];
    const float* gc = (const float*)d_in[11];
    const float* bc = (const float*)d_in[12];
    const float* w3 = (const float*)d_in[13];
    const float* g3 = (const float*)d_in[14];
    const float* b3 = (const float*)d_in[15];
    const int* binv = (const int*)d_in[16];
    const int* bcoords = (const int*)d_in[17];
    const int* cinv = (const int*)d_in[18];
    const int* ccoords = (const int*)d_in[19];
    int N = in_sizes[0] / 5;
    int Nb = in_sizes[17];
    int Nc = in_sizes[19];
    const int B = 4;
    const long GRIDSZ = (long)B * 512 * 48 * 64;

    float* ws = (float*)d_ws;
    long off = 0;
    float* h2 = ws + off;   off += (long)128 * N;
    float* h13 = ws + off;  off += (long)64 * N;   // h1, later reused as h3
    float* grid = ws + off; off += GRIDSZ;
    float* conv = ws + off; off += GRIDSZ;
    float* bacc = ws + off; off += 3L * Nb;
    float* cacc = ws + off; off += 3L * Nc;
    float* stats = ws + off; off += 1280;
    float* wct = ws + off;  off += 9 * 64 * 64;
    float* st1 = stats, *st2 = stats + 128, *st3 = stats + 384, *stC = stats + 512;
    float* ab1 = stats + 640, *ab2 = stats + 768, *ab3 = stats + 1024, *abC = stats + 1152;

    float* out_fea = (float*)d_out;
    unsigned int* out_bev = (unsigned int*)((float*)d_out + (long)N * 64);
    float* out_vc = (float*)d_out + (long)N * 64 + (long)Nb * 64;

    hipMemsetAsync(grid, 0, (size_t)GRIDSZ * 4, stream);
    hipMemsetAsync(bacc, 0, (size_t)3 * Nb * 4, stream);
    hipMemsetAsync(cacc, 0, (size_t)3 * Nc * 4, stream);
    hipMemsetAsync(stats, 0, 1280 * 4, stream);
    hipMemsetAsync(out_bev, 0, (size_t)Nb * 64 * 4, stream);

    int nb256 = (N + 255) / 256;
    k_wct<<<(9 * 64 * 64 + 255) / 256, 256, 0, stream>>>(wc, wct);
    k_scatter_sums<<<nb256, 256, 0, stream>>>(pts, pcyl, binv, cinv, bacc, cacc, N, Nb, Nc);
    k_feat_gemm1<<<nb256, 256, 0, stream>>>(pts, pcyl, cylidx, bevidx, binv, cinv, bacc, cacc, w1, h13, N, Nb, Nc);
    {
        dim3 g(32, 64);
        k_stats_cm<<<g, 256, 0, stream>>>(h13, N, st1);
    }
    k_finalize<<<1, 128, 0, stream>>>(st1, g1, b1, ab1, 64, 1.0f / (float)N);
    k_gemm2<<<nb256, 256, 0, stream>>>(h13, w2, ab1, h2, N);
    {
        dim3 g(32, 128);
        k_stats_cm<<<g, 256, 0, stream>>>(h2, N, st2);
    }
    k_finalize<<<1, 128, 0, stream>>>(st2, g2, b2, ab2, 128, 1.0f / (float)N);
    k_cylmax2<<<(N + 63) / 64, 256, 0, stream>>>(h2, ab2, pts, cylidx, (unsigned int*)grid, N);
    k_conv<<<B * 64 * 6, 256, 0, stream>>>(grid, wct, conv);
    k_stats_cl<<<512, 256, 0, stream>>>(conv, GRIDSZ, stC);
    k_finalize<<<1, 128, 0, stream>>>(stC, gc, bc, abC, 64, 1.0f / (float)(B * 512 * 48));
    k_gather_gemm3<<<nb256, 256, 0, stream>>>(h2, conv, ab2, abC, cylidx, pts, w3, h13, N);
    {
        dim3 g(32, 64);
        k_stats_cm<<<g, 256, 0, stream>>>(h13, N, st3);
    }
    k_finalize<<<1, 128, 0, stream>>>(st3, g3, b3, ab3, 64, 1.0f / (float)N);
    k_out_tile<<<(N + 63) / 64, 256, 0, stream>>>(h13, ab3, binv, out_fea, out_bev, N);
    k_voxcoords<<<(Nb + 255) / 256, 256, 0, stream>>>(bcoords, out_vc, Nb);
}

// Round 3
// 709.002 us; speedup vs baseline: 2.2698x; 1.5020x over previous
//
#include <hip/hip_runtime.h>
#include <math.h>

#define BN_EPS 1e-3f

static constexpr float CR0 = -3.14159265f;
static constexpr float CR1 = -2.0f;
static constexpr float CVS0 = (float)((3.14159265 * 2.0) / 512.0);
static constexpr float CVS1 = (float)(6.0 / 48.0);
#define BEV_SXY (220 * 250)
#define BEV_SY 250

typedef __attribute__((ext_vector_type(8))) __bf16 bf16x8_t;
typedef __attribute__((ext_vector_type(4))) float f32x4_t;

union ABu { uint4 q; unsigned short us[8]; bf16x8_t bf; };

__device__ __forceinline__ float bnr(float x, float a, float b) {
    float v = fmaf(x, a, b);
    return v > 0.f ? v : 0.f;
}
__device__ __forceinline__ float bf2f(unsigned short u) {
    return __uint_as_float(((unsigned)u) << 16);
}
__device__ __forceinline__ unsigned short f2bf(float f) {
    unsigned u = __float_as_uint(f);
    u += 0x7FFFu + ((u >> 16) & 1u);
    return (unsigned short)(u >> 16);
}

// ---- conv weight transpose: wc[o][i][kh][kw] -> wct[(kh*3+kw)][i][o] ----
__global__ void k_wct(const float* __restrict__ wc, float* __restrict__ wct) {
    int tid = blockIdx.x * blockDim.x + threadIdx.x;
    if (tid >= 9 * 64 * 64) return;
    int tap = tid / 4096;
    int rem = tid % 4096;
    int i = rem / 64;
    int o = rem % 64;
    int kh = tap / 3, kw = tap % 3;
    wct[tid] = wc[((o * 64 + i) * 3 + kh) * 3 + kw];
}

// ---- segment sums for means ----
__global__ void k_scatter_sums(const float* __restrict__ pts, const float* __restrict__ pcyl,
                               const int* __restrict__ binv, const int* __restrict__ cinv,
                               float* __restrict__ bacc, float* __restrict__ cacc,
                               int N, int Nb, int Nc) {
    int p = blockIdx.x * blockDim.x + threadIdx.x;
    if (p >= N) return;
    float x = pts[p * 5 + 1], y = pts[p * 5 + 2];
    float ph = pcyl[p * 3 + 0], z = pcyl[p * 3 + 1];
    int bi = binv[p], ci = cinv[p];
    atomicAdd(&bacc[bi], 1.0f);
    atomicAdd(&bacc[Nb + bi], x);
    atomicAdd(&bacc[2 * Nb + bi], y);
    atomicAdd(&cacc[ci], 1.0f);
    atomicAdd(&cacc[Nc + ci], ph);
    atomicAdd(&cacc[2 * Nc + ci], z);
}

// ---- 16-feat build + GEMM1 (16->64), h1 row-major bf16 via LDS transpose ----
__global__ __launch_bounds__(256) void k_feat_gemm1(const float* __restrict__ pts,
        const float* __restrict__ pcyl, const float* __restrict__ cylidx,
        const float* __restrict__ bevidx, const int* __restrict__ binv,
        const int* __restrict__ cinv, const float* __restrict__ bacc,
        const float* __restrict__ cacc, const float* __restrict__ w1,
        unsigned short* __restrict__ h1b, int N, int Nb, int Nc) {
    __shared__ float w1s[1024];
    __shared__ unsigned int tbuf[32 * 260];   // [channel-pair][point-in-block]
    int t = threadIdx.x;
    for (int i = t; i < 1024; i += 256) w1s[i] = w1[i];
    __syncthreads();
    int p = blockIdx.x * 256 + t;
    int pc = min(p, N - 1);
    float x = pts[pc * 5 + 1], y = pts[pc * 5 + 2], z = pts[pc * 5 + 3], inten = pts[pc * 5 + 4];
    float ph = pcyl[pc * 3 + 0], zc = pcyl[pc * 3 + 1], rho = pcyl[pc * 3 + 2];
    float ci0 = cylidx[pc * 2 + 0], ci1 = cylidx[pc * 2 + 1];
    float bi0 = bevidx[pc * 2 + 0], bi1 = bevidx[pc * 2 + 1];
    float bc0 = floorf(bi0), bc1 = floorf(bi1);
    float cc0 = floorf(ci0), cc1 = floorf(ci1);
    int bv = binv[pc], cv = cinv[pc];
    float bcnt = bacc[bv];
    float bmx = bacc[Nb + bv] / bcnt, bmy = bacc[2 * Nb + bv] / bcnt;
    float ccnt = cacc[cv];
    float cmp = cacc[Nc + cv] / ccnt, cmz = cacc[2 * Nc + cv] / ccnt;
    float f[16];
    f[0] = x; f[1] = y; f[2] = z;
    f[3] = ph; f[4] = zc; f[5] = rho;
    f[6] = x - ((bc0 + 0.5f) * 0.32f + 0.0f);
    f[7] = y - ((bc1 + 0.5f) * 0.32f + (-40.0f));
    f[8] = ph - ((cc0 + 0.5f) * CVS0 + CR0);
    f[9] = zc - ((cc1 + 0.5f) * CVS1 + CR1);
    f[10] = x - bmx; f[11] = y - bmy;
    f[12] = ph - cmp; f[13] = zc - cmz;
    f[14] = sqrtf(x * x + y * y + z * z);
    f[15] = inten;
    for (int c2 = 0; c2 < 32; c2++) {
        float s0 = 0.f, s1 = 0.f;
        const float* w0 = &w1s[(2 * c2) * 16];
        const float* w1p = &w1s[(2 * c2 + 1) * 16];
#pragma unroll
        for (int k = 0; k < 16; k++) {
            s0 = fmaf(f[k], w0[k], s0);
            s1 = fmaf(f[k], w1p[k], s1);
        }
        tbuf[c2 * 260 + t] = (unsigned)f2bf(s0) | ((unsigned)f2bf(s1) << 16);
    }
    __syncthreads();
    // coalesced stores: 1024 chunks of 32B
#pragma unroll
    for (int r = 0; r < 4; r++) {
        int cid = t + 256 * r;
        int pp = cid >> 2;
        int gp = blockIdx.x * 256 + pp;
        if (gp < N) {
            int c2b = (cid & 3) * 8;
            uint4 A, Bv;
            A.x = tbuf[(c2b + 0) * 260 + pp];
            A.y = tbuf[(c2b + 1) * 260 + pp];
            A.z = tbuf[(c2b + 2) * 260 + pp];
            A.w = tbuf[(c2b + 3) * 260 + pp];
            Bv.x = tbuf[(c2b + 4) * 260 + pp];
            Bv.y = tbuf[(c2b + 5) * 260 + pp];
            Bv.z = tbuf[(c2b + 6) * 260 + pp];
            Bv.w = tbuf[(c2b + 7) * 260 + pp];
            uint4* dst = (uint4*)(h1b + (long)gp * 64 + (cid & 3) * 16);
            dst[0] = A;
            dst[1] = Bv;
        }
    }
}

// ---- stats over row-major bf16 buffer (channel = index % C) ----
__global__ void k_stats_rm(const unsigned short* __restrict__ buf, long T, int C,
                           float* __restrict__ out) {
    int t = threadIdx.x;
    long g = (long)blockIdx.x * 256 + t;
    long stride = (long)gridDim.x * 256;   // must be multiple of C (256*512)
    float s = 0.f, q = 0.f;
    for (long i = g; i < T; i += stride) {
        float v = bf2f(buf[i]);
        s += v;
        q = fmaf(v, v, q);
    }
    __shared__ float ls[256], lq[256];
    ls[t] = s; lq[t] = q;
    __syncthreads();
    if (t < C) {
        for (int o = t + C; o < 256; o += C) { s += ls[o]; q += lq[o]; }
        atomicAdd(&out[t], s);
        atomicAdd(&out[C + t], q);
    }
}

// ---- stats for channel-last fp32 buffer (conv output, 64 ch) ----
__global__ void k_stats_cl(const float* __restrict__ buf, long T, float* __restrict__ out) {
    int t = threadIdx.x;
    int c = t & 63;
    float s = 0.f, q = 0.f;
    for (long i = (long)blockIdx.x * blockDim.x + t; i < T; i += (long)gridDim.x * blockDim.x) {
        float v = buf[i];
        s += v;
        q = fmaf(v, v, q);
    }
    __shared__ float ls[256], lq[256];
    ls[t] = s; lq[t] = q;
    __syncthreads();
    if (t < 64) {
        s = ls[t] + ls[t + 64] + ls[t + 128] + ls[t + 192];
        q = lq[t] + lq[t + 64] + lq[t + 128] + lq[t + 192];
        atomicAdd(&out[c], s);
        atomicAdd(&out[64 + c], q);
    }
}

// ---- BN finalize ----
__global__ void k_finalize(const float* __restrict__ st, const float* __restrict__ g,
                           const float* __restrict__ b, float* __restrict__ ab, int C, float invn) {
    int c = blockIdx.x * blockDim.x + threadIdx.x;
    if (c >= C) return;
    float m = st[c] * invn;
    float v = st[C + c] * invn - m * m;
    float a = g[c] * rsqrtf(v + BN_EPS);
    ab[c] = a;
    ab[C + c] = b[c] - m * a;
}

// ---- GEMM2 via MFMA: h2[p][o] = sum_c BNReLU(h1[p][c]) * w2[o][c]; raw bf16 out ----
__global__ __launch_bounds__(256, 2) void k_gemm2_mfma(const unsigned short* __restrict__ h1b,
        const float* __restrict__ w2, const float* __restrict__ ab1,
        unsigned short* __restrict__ h2b, int N) {
    int lane = threadIdx.x & 63;
    int c = lane & 15, quad = lane >> 4;
    int wid = (blockIdx.x * 256 + threadIdx.x) >> 6;
    int nw = gridDim.x * 4;
    bf16x8_t Bf[8][2];
#pragma unroll
    for (int tt = 0; tt < 8; tt++)
#pragma unroll
        for (int kc = 0; kc < 2; kc++) {
            const float* wr = w2 + (tt * 16 + c) * 64 + kc * 32 + quad * 8;
            float4 w0 = *(const float4*)wr;
            float4 w1 = *(const float4*)(wr + 4);
            ABu tmp;
            tmp.us[0] = f2bf(w0.x); tmp.us[1] = f2bf(w0.y);
            tmp.us[2] = f2bf(w0.z); tmp.us[3] = f2bf(w0.w);
            tmp.us[4] = f2bf(w1.x); tmp.us[5] = f2bf(w1.y);
            tmp.us[6] = f2bf(w1.z); tmp.us[7] = f2bf(w1.w);
            Bf[tt][kc] = tmp.bf;
        }
    float a1[16], b1[16];
#pragma unroll
    for (int kc = 0; kc < 2; kc++)
#pragma unroll
        for (int j = 0; j < 8; j++) {
            int ch = kc * 32 + quad * 8 + j;
            a1[kc * 8 + j] = ab1[ch];
            b1[kc * 8 + j] = ab1[64 + ch];
        }
    int ntiles = (N + 15) >> 4;
    for (int tile = wid; tile < ntiles; tile += nw) {
        int p0 = tile * 16;
        int pa = min(p0 + c, N - 1);
        bf16x8_t Af[2];
#pragma unroll
        for (int kc = 0; kc < 2; kc++) {
            ABu u;
            u.q = *(const uint4*)(h1b + (long)pa * 64 + kc * 32 + quad * 8);
            ABu o;
#pragma unroll
            for (int j = 0; j < 8; j++)
                o.us[j] = f2bf(bnr(bf2f(u.us[j]), a1[kc * 8 + j], b1[kc * 8 + j]));
            Af[kc] = o.bf;
        }
        f32x4_t acc[8];
#pragma unroll
        for (int tt = 0; tt < 8; tt++) acc[tt] = (f32x4_t){0.f, 0.f, 0.f, 0.f};
#pragma unroll
        for (int tt = 0; tt < 8; tt++) {
            acc[tt] = __builtin_amdgcn_mfma_f32_16x16x32_bf16(Af[0], Bf[tt][0], acc[tt], 0, 0, 0);
            acc[tt] = __builtin_amdgcn_mfma_f32_16x16x32_bf16(Af[1], Bf[tt][1], acc[tt], 0, 0, 0);
        }
#pragma unroll
        for (int tt = 0; tt < 8; tt++)
#pragma unroll
            for (int r = 0; r < 4; r++) {
                int pr = p0 + quad * 4 + r;
                if (pr < N) h2b[(long)pr * 128 + tt * 16 + c] = f2bf(acc[tt][r]);
            }
    }
}

// ---- scatter-max into dense cyl grid; wave per point, lane = channel ----
__global__ __launch_bounds__(256) void k_cylmax3(const unsigned short* __restrict__ h2b,
        const float* __restrict__ ab2, const float* __restrict__ pts,
        const float* __restrict__ cylidx, unsigned int* __restrict__ grid, int N) {
    int t = threadIdx.x, lane = t & 63, w = t >> 6;
    float a = ab2[lane], bb = ab2[128 + lane];
    int p0 = blockIdx.x * 64 + w * 16;
    for (int j = 0; j < 16; j++) {
        int p = p0 + j;
        if (p >= N) break;
        float v = bnr(bf2f(h2b[(long)p * 128 + lane]), a, bb);
        int b = (int)pts[p * 5];
        int cx = (int)floorf(cylidx[p * 2]);
        int cy = (int)floorf(cylidx[p * 2 + 1]);
        unsigned int* cell = grid + (((long)b * 512 + cx) * 48 + cy) * 64;
        if (v > 0.f) {
            unsigned uv = __float_as_uint(v);
            unsigned cur = cell[lane];
            if (uv > cur) atomicMax(&cell[lane], uv);
        }
    }
}

// ---- 3x3 SAME conv, NHWC (B,512,48,64), fp32 ----
__global__ __launch_bounds__(256) void k_conv(const float* __restrict__ gridin,
                                              const float* __restrict__ wct,
                                              float* __restrict__ out) {
    __shared__ float in_s[64 * 65];
    __shared__ float w_s[64 * 64];
    int t = threadIdx.x;
    int bid = blockIdx.x;
    int b = bid / (64 * 6);
    int r = bid % (64 * 6);
    int h0 = (r / 6) * 8, w0 = (r % 6) * 8;
    float acc[4][4];
#pragma unroll
    for (int i = 0; i < 4; i++)
#pragma unroll
        for (int j = 0; j < 4; j++) acc[i][j] = 0.f;
    int tp = t & 15, to = t >> 4;
    for (int tap = 0; tap < 9; tap++) {
        int dh = tap / 3 - 1, dw = tap % 3 - 1;
        __syncthreads();
#pragma unroll
        for (int i = 0; i < 16; i++) w_s[t + i * 256] = wct[tap * 4096 + t + i * 256];
#pragma unroll
        for (int i = 0; i < 4; i++) {
            int flat = t + i * 256;
            int pix = flat >> 4, c4 = flat & 15;
            int ph = pix >> 3, pw = pix & 7;
            int hh = h0 + ph + dh, ww = w0 + pw + dw;
            float4 v = make_float4(0.f, 0.f, 0.f, 0.f);
            if (hh >= 0 && hh < 512 && ww >= 0 && ww < 48)
                v = *(const float4*)&gridin[(((long)b * 512 + hh) * 48 + ww) * 64 + c4 * 4];
            in_s[pix * 65 + c4 * 4 + 0] = v.x;
            in_s[pix * 65 + c4 * 4 + 1] = v.y;
            in_s[pix * 65 + c4 * 4 + 2] = v.z;
            in_s[pix * 65 + c4 * 4 + 3] = v.w;
        }
        __syncthreads();
#pragma unroll 4
        for (int ic = 0; ic < 64; ic++) {
            float i0 = in_s[(tp * 4 + 0) * 65 + ic];
            float i1 = in_s[(tp * 4 + 1) * 65 + ic];
            float i2 = in_s[(tp * 4 + 2) * 65 + ic];
            float i3 = in_s[(tp * 4 + 3) * 65 + ic];
            float4 w = *(const float4*)&w_s[ic * 64 + to * 4];
            acc[0][0] = fmaf(i0, w.x, acc[0][0]); acc[0][1] = fmaf(i0, w.y, acc[0][1]);
            acc[0][2] = fmaf(i0, w.z, acc[0][2]); acc[0][3] = fmaf(i0, w.w, acc[0][3]);
            acc[1][0] = fmaf(i1, w.x, acc[1][0]); acc[1][1] = fmaf(i1, w.y, acc[1][1]);
            acc[1][2] = fmaf(i1, w.z, acc[1][2]); acc[1][3] = fmaf(i1, w.w, acc[1][3]);
            acc[2][0] = fmaf(i2, w.x, acc[2][0]); acc[2][1] = fmaf(i2, w.y, acc[2][1]);
            acc[2][2] = fmaf(i2, w.z, acc[2][2]); acc[2][3] = fmaf(i2, w.w, acc[2][3]);
            acc[3][0] = fmaf(i3, w.x, acc[3][0]); acc[3][1] = fmaf(i3, w.y, acc[3][1]);
            acc[3][2] = fmaf(i3, w.z, acc[3][2]); acc[3][3] = fmaf(i3, w.w, acc[3][3]);
        }
    }
#pragma unroll
    for (int i = 0; i < 4; i++) {
        int pix = tp * 4 + i;
        int ph = pix >> 3, pw = pix & 7;
        float4 v = make_float4(acc[i][0], acc[i][1], acc[i][2], acc[i][3]);
        *(float4*)&out[(((long)b * 512 + h0 + ph) * 48 + w0 + pw) * 64 + to * 4] = v;
    }
}

// ---- bilinear gather + GEMM3 via MFMA -> h3 row-major raw bf16 ----
__global__ __launch_bounds__(256, 2) void k_gather3_mfma(const unsigned short* __restrict__ h2b,
        const float* __restrict__ conv, const float* __restrict__ ab2,
        const float* __restrict__ abC, const float* __restrict__ cylidx,
        const float* __restrict__ pts, const float* __restrict__ w3,
        unsigned short* __restrict__ h3b, int N) {
    int lane = threadIdx.x & 63;
    int c = lane & 15, quad = lane >> 4;
    int wid = (blockIdx.x * 256 + threadIdx.x) >> 6;
    int nw = gridDim.x * 4;
    bf16x8_t Bf[4][4];
#pragma unroll
    for (int tt = 0; tt < 4; tt++)
#pragma unroll
        for (int kc = 0; kc < 4; kc++) {
            const float* wr = w3 + (tt * 16 + c) * 128 + kc * 32 + quad * 8;
            float4 w0 = *(const float4*)wr;
            float4 w1 = *(const float4*)(wr + 4);
            ABu tmp;
            tmp.us[0] = f2bf(w0.x); tmp.us[1] = f2bf(w0.y);
            tmp.us[2] = f2bf(w0.z); tmp.us[3] = f2bf(w0.w);
            tmp.us[4] = f2bf(w1.x); tmp.us[5] = f2bf(w1.y);
            tmp.us[6] = f2bf(w1.z); tmp.us[7] = f2bf(w1.w);
            Bf[tt][kc] = tmp.bf;
        }
    float a2[16], b2[16], aC[16], bC[16];
#pragma unroll
    for (int kc = 0; kc < 2; kc++)
#pragma unroll
        for (int j = 0; j < 8; j++) {
            int kk = kc * 32 + quad * 8 + j;
            a2[kc * 8 + j] = ab2[64 + kk];
            b2[kc * 8 + j] = ab2[192 + kk];
            aC[kc * 8 + j] = abC[kk];
            bC[kc * 8 + j] = abC[64 + kk];
        }
    int ntiles = (N + 15) >> 4;
    for (int tile = wid; tile < ntiles; tile += nw) {
        int p0 = tile * 16;
        int p = min(p0 + c, N - 1);
        float yq = cylidx[p * 2], xq = cylidx[p * 2 + 1];
        int b = (int)pts[p * 5];
        int xf = (int)floorf(xq), yf = (int)floorf(yq);
        int x0 = min(max(xf, 0), 47);
        int x1 = min(max(xf + 1, 0), 47);
        int y0 = min(max(yf, 0), 511);
        int y1 = min(max(yf + 1, 0), 511);
        float x0f = (float)x0, x1f = (float)x1, y0f = (float)y0, y1f = (float)y1;
        float wa = (x1f - xq) * (y1f - yq);
        float wb = (x1f - xq) * (yq - y0f);
        float wc2 = (xq - x0f) * (y1f - yq);
        float wd = (xq - x0f) * (yq - y0f);
        const float* Ia = conv + (((long)b * 512 + y0) * 48 + x0) * 64;
        const float* Ib = conv + (((long)b * 512 + y1) * 48 + x0) * 64;
        const float* Ic = conv + (((long)b * 512 + y0) * 48 + x1) * 64;
        const float* Id = conv + (((long)b * 512 + y1) * 48 + x1) * 64;
        bf16x8_t Af[4];
#pragma unroll
        for (int kc = 0; kc < 2; kc++) {
            ABu u;
            u.q = *(const uint4*)(h2b + (long)p * 128 + 64 + kc * 32 + quad * 8);
            ABu o;
#pragma unroll
            for (int j = 0; j < 8; j++)
                o.us[j] = f2bf(bnr(bf2f(u.us[j]), a2[kc * 8 + j], b2[kc * 8 + j]));
            Af[kc] = o.bf;
        }
#pragma unroll
        for (int kc = 0; kc < 2; kc++) {
            int cb = kc * 32 + quad * 8;
            float va[8], vb[8], vc[8], vd[8];
            *(float4*)&va[0] = *(const float4*)(Ia + cb); *(float4*)&va[4] = *(const float4*)(Ia + cb + 4);
            *(float4*)&vb[0] = *(const float4*)(Ib + cb); *(float4*)&vb[4] = *(const float4*)(Ib + cb + 4);
            *(float4*)&vc[0] = *(const float4*)(Ic + cb); *(float4*)&vc[4] = *(const float4*)(Ic + cb + 4);
            *(float4*)&vd[0] = *(const float4*)(Id + cb); *(float4*)&vd[4] = *(const float4*)(Id + cb + 4);
            ABu o;
#pragma unroll
            for (int j = 0; j < 8; j++) {
                float aa = aC[kc * 8 + j], bbv = bC[kc * 8 + j];
                float v = wa * bnr(va[j], aa, bbv) + wb * bnr(vb[j], aa, bbv)
                        + wc2 * bnr(vc[j], aa, bbv) + wd * bnr(vd[j], aa, bbv);
                o.us[j] = f2bf(v);
            }
            Af[2 + kc] = o.bf;
        }
        f32x4_t acc[4];
#pragma unroll
        for (int tt = 0; tt < 4; tt++) acc[tt] = (f32x4_t){0.f, 0.f, 0.f, 0.f};
#pragma unroll
        for (int tt = 0; tt < 4; tt++)
#pragma unroll
            for (int kc = 0; kc < 4; kc++)
                acc[tt] = __builtin_amdgcn_mfma_f32_16x16x32_bf16(Af[kc], Bf[tt][kc], acc[tt], 0, 0, 0);
#pragma unroll
        for (int tt = 0; tt < 4; tt++)
#pragma unroll
            for (int r = 0; r < 4; r++) {
                int pr = p0 + quad * 4 + r;
                if (pr < N) h3b[(long)pr * 64 + tt * 16 + c] = f2bf(acc[tt][r]);
            }
    }
}

// ---- final BN-ReLU -> out_fea fp32 + bev scatter-max; wave per point ----
__global__ __launch_bounds__(256) void k_out_tile2(const unsigned short* __restrict__ h3b,
        const float* __restrict__ ab3, const int* __restrict__ binv,
        float* __restrict__ out_fea, unsigned int* __restrict__ out_bev, int N) {
    int t = threadIdx.x, lane = t & 63, w = t >> 6;
    float a = ab3[lane], bb = ab3[64 + lane];
    int p0 = blockIdx.x * 64 + w * 16;
    for (int j = 0; j < 16; j++) {
        int p = p0 + j;
        if (p >= N) break;
        float v = bnr(bf2f(h3b[(long)p * 64 + lane]), a, bb);
        out_fea[(long)p * 64 + lane] = v;
        int bi = binv[p];
        if (v > 0.f) {
            unsigned uv = __float_as_uint(v);
            unsigned* cell = out_bev + (long)bi * 64;
            unsigned cur = cell[lane];
            if (uv > cur) atomicMax(&cell[lane], uv);
        }
    }
}

// ---- voxel coords ----
__global__ void k_voxcoords(const int* __restrict__ coords, float* __restrict__ out, int Nb) {
    int i = blockIdx.x * blockDim.x + threadIdx.x;
    if (i >= Nb) return;
    int c = coords[i];
    int vb = c / BEV_SXY;
    int rem = c % BEV_SXY;
    int vx = rem / BEV_SY;
    int vy = rem % BEV_SY;
    out[i * 4 + 0] = (float)vb;
    out[i * 4 + 1] = 0.f;
    out[i * 4 + 2] = (float)vy;
    out[i * 4 + 3] = (float)vx;
}

extern "C" void kernel_launch(void* const* d_in, const int* in_sizes, int n_in,
                              void* d_out, int out_size, void* d_ws, size_t ws_size,
                              hipStream_t stream) {
    const float* pts = (const float*)d_in[0];
    const float* pcyl = (const float*)d_in[1];
    const float* cylidx = (const float*)d_in[2];
    const float* bevidx = (const float*)d_in[3];
    const float* w1 = (const float*)d_in[4];
    const float* g1 = (const float*)d_in[5];
    const float* b1 = (const float*)d_in[6];
    const float* w2 = (const float*)d_in[7];
    const float* g2 = (const float*)d_in[8];
    const float* b2 = (const float*)d_in[9];
    const float* wc = (const float*)d_in[10];
    const float* gc = (const float*)d_in[11];
    const float* bc = (const float*)d_in[12];
    const float* w3 = (const float*)d_in[13];
    const float* g3 = (const float*)d_in[14];
    const float* b3 = (const float*)d_in[15];
    const int* binv = (const int*)d_in[16];
    const int* bcoords = (const int*)d_in[17];
    const int* cinv = (const int*)d_in[18];
    const int* ccoords = (const int*)d_in[19];
    int N = in_sizes[0] / 5;
    int Nb = in_sizes[17];
    int Nc = in_sizes[19];
    const int B = 4;
    const long GRIDSZ = (long)B * 512 * 48 * 64;

    char* wsb = (char*)d_ws;
    unsigned short* h2b = (unsigned short*)wsb;                     // 128N bf16
    unsigned short* h13b = (unsigned short*)(wsb + 256L * N);       // 64N bf16 (h1, then h3)
    float* grid = (float*)(wsb + 384L * N);
    float* conv = grid + GRIDSZ;
    float* bacc = conv + GRIDSZ;
    float* cacc = bacc + 3L * Nb;
    float* stats = cacc + 3L * Nc;
    float* wct = stats + 1280;
    float* st1 = stats, *st2 = stats + 128, *st3 = stats + 384, *stC = stats + 512;
    float* ab1 = stats + 640, *ab2 = stats + 768, *ab3 = stats + 1024, *abC = stats + 1152;

    float* out_fea = (float*)d_out;
    unsigned int* out_bev = (unsigned int*)((float*)d_out + (long)N * 64);
    float* out_vc = (float*)d_out + (long)N * 64 + (long)Nb * 64;

    hipMemsetAsync(grid, 0, (size_t)GRIDSZ * 4, stream);
    hipMemsetAsync(bacc, 0, (size_t)3 * Nb * 4, stream);
    hipMemsetAsync(cacc, 0, (size_t)3 * Nc * 4, stream);
    hipMemsetAsync(stats, 0, 1280 * 4, stream);
    hipMemsetAsync(out_bev, 0, (size_t)Nb * 64 * 4, stream);

    int nb256 = (N + 255) / 256;
    k_wct<<<(9 * 64 * 64 + 255) / 256, 256, 0, stream>>>(wc, wct);
    k_scatter_sums<<<nb256, 256, 0, stream>>>(pts, pcyl, binv, cinv, bacc, cacc, N, Nb, Nc);
    k_feat_gemm1<<<nb256, 256, 0, stream>>>(pts, pcyl, cylidx, bevidx, binv, cinv, bacc, cacc, w1, h13b, N, Nb, Nc);
    k_stats_rm<<<512, 256, 0, stream>>>(h13b, 64L * N, 64, st1);
    k_finalize<<<1, 128, 0, stream>>>(st1, g1, b1, ab1, 64, 1.0f / (float)N);
    k_gemm2_mfma<<<512, 256, 0, stream>>>(h13b, w2, ab1, h2b, N);
    k_stats_rm<<<512, 256, 0, stream>>>(h2b, 128L * N, 128, st2);
    k_finalize<<<1, 128, 0, stream>>>(st2, g2, b2, ab2, 128, 1.0f / (float)N);
    k_cylmax3<<<(N + 63) / 64, 256, 0, stream>>>(h2b, ab2, pts, cylidx, (unsigned int*)grid, N);
    k_conv<<<B * 64 * 6, 256, 0, stream>>>(grid, wct, conv);
    k_stats_cl<<<512, 256, 0, stream>>>(conv, GRIDSZ, stC);
    k_finalize<<<1, 128, 0, stream>>>(stC, gc, bc, abC, 64, 1.0f / (float)(B * 512 * 48));
    k_gather3_mfma<<<512, 256, 0, stream>>>(h2b, conv, ab2, abC, cylidx, pts, w3, h13b, N);
    k_stats_rm<<<512, 256, 0, stream>>>(h13b, 64L * N, 64, st3);
    k_finalize<<<1, 128, 0, stream>>>(st3, g3, b3, ab3, 64, 1.0f / (float)N);
    k_out_tile2<<<(N + 63) / 64, 256, 0, stream>>>(h13b, ab3, binv, out_fea, out_bev, N);
    k_voxcoords<<<(Nb + 255) / 256, 256, 0, stream>>>(bcoords, out_vc, Nb);
}

// Round 4
// 661.541 us; speedup vs baseline: 2.4326x; 1.0717x over previous
//
#include <hip/hip_runtime.h>
#include <math.h>

#define BN_EPS 1e-3f

static constexpr float CR0 = -3.14159265f;
static constexpr float CR1 = -2.0f;
static constexpr float CVS0 = (float)((3.14159265 * 2.0) / 512.0);
static constexpr float CVS1 = (float)(6.0 / 48.0);
#define BEV_SXY (220 * 250)
#define BEV_SY 250

typedef __attribute__((ext_vector_type(8))) __bf16 bf16x8_t;
typedef __attribute__((ext_vector_type(4))) float f32x4_t;

union ABu { uint4 q; unsigned short us[8]; bf16x8_t bf; };

__device__ __forceinline__ float bnr(float x, float a, float b) {
    float v = fmaf(x, a, b);
    return v > 0.f ? v : 0.f;
}
__device__ __forceinline__ float bf2f(unsigned short u) {
    return __uint_as_float(((unsigned)u) << 16);
}
__device__ __forceinline__ unsigned short f2bf(float f) {
    unsigned u = __float_as_uint(f);
    u += 0x7FFFu + ((u >> 16) & 1u);
    return (unsigned short)(u >> 16);
}

// ---- conv weight transpose: wc[o][i][kh][kw] -> wct[(kh*3+kw)][i][o] ----
__global__ void k_wct(const float* __restrict__ wc, float* __restrict__ wct) {
    int tid = blockIdx.x * blockDim.x + threadIdx.x;
    if (tid >= 9 * 64 * 64) return;
    int tap = tid / 4096;
    int rem = tid % 4096;
    int i = rem / 64;
    int o = rem % 64;
    int kh = tap / 3, kw = tap % 3;
    wct[tid] = wc[((o * 64 + i) * 3 + kh) * 3 + kw];
}

// ---- segment sums for means ----
__global__ void k_scatter_sums(const float* __restrict__ pts, const float* __restrict__ pcyl,
                               const int* __restrict__ binv, const int* __restrict__ cinv,
                               float* __restrict__ bacc, float* __restrict__ cacc,
                               int N, int Nb, int Nc) {
    int p = blockIdx.x * blockDim.x + threadIdx.x;
    if (p >= N) return;
    float x = pts[p * 5 + 1], y = pts[p * 5 + 2];
    float ph = pcyl[p * 3 + 0], z = pcyl[p * 3 + 1];
    int bi = binv[p], ci = cinv[p];
    atomicAdd(&bacc[bi], 1.0f);
    atomicAdd(&bacc[Nb + bi], x);
    atomicAdd(&bacc[2 * Nb + bi], y);
    atomicAdd(&cacc[ci], 1.0f);
    atomicAdd(&cacc[Nc + ci], ph);
    atomicAdd(&cacc[2 * Nc + ci], z);
}

// ---- 16-feat build + GEMM1 (16->64), h1 row-major bf16 via LDS transpose ----
__global__ __launch_bounds__(256) void k_feat_gemm1(const float* __restrict__ pts,
        const float* __restrict__ pcyl, const float* __restrict__ cylidx,
        const float* __restrict__ bevidx, const int* __restrict__ binv,
        const int* __restrict__ cinv, const float* __restrict__ bacc,
        const float* __restrict__ cacc, const float* __restrict__ w1,
        unsigned short* __restrict__ h1b, int N, int Nb, int Nc) {
    __shared__ float w1s[1024];
    __shared__ unsigned int tbuf[32 * 260];
    int t = threadIdx.x;
    for (int i = t; i < 1024; i += 256) w1s[i] = w1[i];
    __syncthreads();
    int p = blockIdx.x * 256 + t;
    int pc = min(p, N - 1);
    float x = pts[pc * 5 + 1], y = pts[pc * 5 + 2], z = pts[pc * 5 + 3], inten = pts[pc * 5 + 4];
    float ph = pcyl[pc * 3 + 0], zc = pcyl[pc * 3 + 1], rho = pcyl[pc * 3 + 2];
    float ci0 = cylidx[pc * 2 + 0], ci1 = cylidx[pc * 2 + 1];
    float bi0 = bevidx[pc * 2 + 0], bi1 = bevidx[pc * 2 + 1];
    float bc0 = floorf(bi0), bc1 = floorf(bi1);
    float cc0 = floorf(ci0), cc1 = floorf(ci1);
    int bv = binv[pc], cv = cinv[pc];
    float bcnt = bacc[bv];
    float bmx = bacc[Nb + bv] / bcnt, bmy = bacc[2 * Nb + bv] / bcnt;
    float ccnt = cacc[cv];
    float cmp = cacc[Nc + cv] / ccnt, cmz = cacc[2 * Nc + cv] / ccnt;
    float f[16];
    f[0] = x; f[1] = y; f[2] = z;
    f[3] = ph; f[4] = zc; f[5] = rho;
    f[6] = x - ((bc0 + 0.5f) * 0.32f + 0.0f);
    f[7] = y - ((bc1 + 0.5f) * 0.32f + (-40.0f));
    f[8] = ph - ((cc0 + 0.5f) * CVS0 + CR0);
    f[9] = zc - ((cc1 + 0.5f) * CVS1 + CR1);
    f[10] = x - bmx; f[11] = y - bmy;
    f[12] = ph - cmp; f[13] = zc - cmz;
    f[14] = sqrtf(x * x + y * y + z * z);
    f[15] = inten;
    for (int c2 = 0; c2 < 32; c2++) {
        float s0 = 0.f, s1 = 0.f;
        const float* w0 = &w1s[(2 * c2) * 16];
        const float* w1p = &w1s[(2 * c2 + 1) * 16];
#pragma unroll
        for (int k = 0; k < 16; k++) {
            s0 = fmaf(f[k], w0[k], s0);
            s1 = fmaf(f[k], w1p[k], s1);
        }
        tbuf[c2 * 260 + t] = (unsigned)f2bf(s0) | ((unsigned)f2bf(s1) << 16);
    }
    __syncthreads();
#pragma unroll
    for (int r = 0; r < 4; r++) {
        int cid = t + 256 * r;
        int pp = cid >> 2;
        int gp = blockIdx.x * 256 + pp;
        if (gp < N) {
            int c2b = (cid & 3) * 8;
            uint4 A, Bv;
            A.x = tbuf[(c2b + 0) * 260 + pp];
            A.y = tbuf[(c2b + 1) * 260 + pp];
            A.z = tbuf[(c2b + 2) * 260 + pp];
            A.w = tbuf[(c2b + 3) * 260 + pp];
            Bv.x = tbuf[(c2b + 4) * 260 + pp];
            Bv.y = tbuf[(c2b + 5) * 260 + pp];
            Bv.z = tbuf[(c2b + 6) * 260 + pp];
            Bv.w = tbuf[(c2b + 7) * 260 + pp];
            uint4* dst = (uint4*)(h1b + (long)gp * 64 + (cid & 3) * 16);
            dst[0] = A;
            dst[1] = Bv;
        }
    }
}

// ---- stats over row-major bf16 buffer (channel = index % C) ----
__global__ void k_stats_rm(const unsigned short* __restrict__ buf, long T, int C,
                           float* __restrict__ out) {
    int t = threadIdx.x;
    long g = (long)blockIdx.x * 256 + t;
    long stride = (long)gridDim.x * 256;
    float s = 0.f, q = 0.f;
    for (long i = g; i < T; i += stride) {
        float v = bf2f(buf[i]);
        s += v;
        q = fmaf(v, v, q);
    }
    __shared__ float ls[256], lq[256];
    ls[t] = s; lq[t] = q;
    __syncthreads();
    if (t < C) {
        for (int o = t + C; o < 256; o += C) { s += ls[o]; q += lq[o]; }
        atomicAdd(&out[t], s);
        atomicAdd(&out[C + t], q);
    }
}

// ---- BN finalize ----
__global__ void k_finalize(const float* __restrict__ st, const float* __restrict__ g,
                           const float* __restrict__ b, float* __restrict__ ab, int C, float invn) {
    int c = blockIdx.x * blockDim.x + threadIdx.x;
    if (c >= C) return;
    float m = st[c] * invn;
    float v = st[C + c] * invn - m * m;
    float a = g[c] * rsqrtf(v + BN_EPS);
    ab[c] = a;
    ab[C + c] = b[c] - m * a;
}

// ---- GEMM2 via MFMA ----
__global__ __launch_bounds__(256, 2) void k_gemm2_mfma(const unsigned short* __restrict__ h1b,
        const float* __restrict__ w2, const float* __restrict__ ab1,
        unsigned short* __restrict__ h2b, int N) {
    int lane = threadIdx.x & 63;
    int c = lane & 15, quad = lane >> 4;
    int wid = (blockIdx.x * 256 + threadIdx.x) >> 6;
    int nw = gridDim.x * 4;
    bf16x8_t Bf[8][2];
#pragma unroll
    for (int tt = 0; tt < 8; tt++)
#pragma unroll
        for (int kc = 0; kc < 2; kc++) {
            const float* wr = w2 + (tt * 16 + c) * 64 + kc * 32 + quad * 8;
            float4 w0 = *(const float4*)wr;
            float4 w1 = *(const float4*)(wr + 4);
            ABu tmp;
            tmp.us[0] = f2bf(w0.x); tmp.us[1] = f2bf(w0.y);
            tmp.us[2] = f2bf(w0.z); tmp.us[3] = f2bf(w0.w);
            tmp.us[4] = f2bf(w1.x); tmp.us[5] = f2bf(w1.y);
            tmp.us[6] = f2bf(w1.z); tmp.us[7] = f2bf(w1.w);
            Bf[tt][kc] = tmp.bf;
        }
    float a1[16], b1[16];
#pragma unroll
    for (int kc = 0; kc < 2; kc++)
#pragma unroll
        for (int j = 0; j < 8; j++) {
            int ch = kc * 32 + quad * 8 + j;
            a1[kc * 8 + j] = ab1[ch];
            b1[kc * 8 + j] = ab1[64 + ch];
        }
    int ntiles = (N + 15) >> 4;
    for (int tile = wid; tile < ntiles; tile += nw) {
        int p0 = tile * 16;
        int pa = min(p0 + c, N - 1);
        bf16x8_t Af[2];
#pragma unroll
        for (int kc = 0; kc < 2; kc++) {
            ABu u;
            u.q = *(const uint4*)(h1b + (long)pa * 64 + kc * 32 + quad * 8);
            ABu o;
#pragma unroll
            for (int j = 0; j < 8; j++)
                o.us[j] = f2bf(bnr(bf2f(u.us[j]), a1[kc * 8 + j], b1[kc * 8 + j]));
            Af[kc] = o.bf;
        }
        f32x4_t acc[8];
#pragma unroll
        for (int tt = 0; tt < 8; tt++) acc[tt] = (f32x4_t){0.f, 0.f, 0.f, 0.f};
#pragma unroll
        for (int tt = 0; tt < 8; tt++) {
            acc[tt] = __builtin_amdgcn_mfma_f32_16x16x32_bf16(Af[0], Bf[tt][0], acc[tt], 0, 0, 0);
            acc[tt] = __builtin_amdgcn_mfma_f32_16x16x32_bf16(Af[1], Bf[tt][1], acc[tt], 0, 0, 0);
        }
#pragma unroll
        for (int tt = 0; tt < 8; tt++)
#pragma unroll
            for (int r = 0; r < 4; r++) {
                int pr = p0 + quad * 4 + r;
                if (pr < N) h2b[(long)pr * 128 + tt * 16 + c] = f2bf(acc[tt][r]);
            }
    }
}

// ---- scatter-max into dense cyl grid; ONE WAVE PER POINT (lane = channel) ----
__global__ __launch_bounds__(256) void k_cylmax4(const unsigned short* __restrict__ h2b,
        const float* __restrict__ ab2, const float* __restrict__ pts,
        const float* __restrict__ cylidx, unsigned int* __restrict__ grid, int N) {
    int t = threadIdx.x, lane = t & 63, w = t >> 6;
    int p = blockIdx.x * 4 + w;
    if (p >= N) return;
    float a = ab2[lane], bb = ab2[128 + lane];
    float v = bnr(bf2f(h2b[(long)p * 128 + lane]), a, bb);
    int b = (int)pts[p * 5];
    int cx = (int)floorf(cylidx[p * 2]);
    int cy = (int)floorf(cylidx[p * 2 + 1]);
    unsigned int* cell = grid + (((long)b * 512 + cx) * 48 + cy) * 64;
    if (v > 0.f) {
        unsigned uv = __float_as_uint(v);
        unsigned cur = cell[lane];
        if (uv > cur) atomicMax(&cell[lane], uv);
    }
}

// ---- fp32 grid -> bf16 grid ----
__global__ void k_g2b(const float* __restrict__ g, unsigned short* __restrict__ gb, long T) {
    long i = ((long)blockIdx.x * 256 + threadIdx.x) * 8;
    if (i >= T) return;
    float4 a = *(const float4*)(g + i);
    float4 b = *(const float4*)(g + i + 4);
    ABu o;
    o.us[0] = f2bf(a.x); o.us[1] = f2bf(a.y); o.us[2] = f2bf(a.z); o.us[3] = f2bf(a.w);
    o.us[4] = f2bf(b.x); o.us[5] = f2bf(b.y); o.us[6] = f2bf(b.z); o.us[7] = f2bf(b.w);
    *(uint4*)(gb + i) = o.q;
}

// ---- 3x3 conv as implicit-GEMM MFMA: bf16 grid (B,512,48,64) -> bf16 out ----
// wave = 16-pixel row segment x 16 out-channels; K = 9 taps x 64 in-ch.
__global__ __launch_bounds__(256, 2) void k_conv_mfma(const unsigned short* __restrict__ gb,
        const float* __restrict__ wct, unsigned short* __restrict__ cb) {
    int lane = threadIdx.x & 63;
    int n = lane & 15, quad = lane >> 4;
    int tt = threadIdx.x >> 6;           // out-channel block (0..3), one per wave
    bf16x8_t Bf[9][2];
#pragma unroll
    for (int tap = 0; tap < 9; tap++)
#pragma unroll
        for (int kc = 0; kc < 2; kc++) {
            ABu tmp;
#pragma unroll
            for (int j = 0; j < 8; j++) {
                int ic = kc * 32 + quad * 8 + j;
                tmp.us[j] = f2bf(wct[tap * 4096 + ic * 64 + tt * 16 + n]);
            }
            Bf[tap][kc] = tmp.bf;
        }
    const int ntiles = 4 * 512 * 3;
    for (int ti = blockIdx.x; ti < ntiles; ti += gridDim.x) {
        int b = ti / (512 * 3);
        int rr = ti % (512 * 3);
        int r = rr / 3, seg = rr % 3;
        int w0 = seg * 16;
        f32x4_t acc = (f32x4_t){0.f, 0.f, 0.f, 0.f};
#pragma unroll
        for (int tap = 0; tap < 9; tap++) {
            int dh = tap / 3 - 1, dw = tap % 3 - 1;
            int hh = r + dh, ww = w0 + n + dw;
            bool ok = (hh >= 0) && (hh < 512) && (ww >= 0) && (ww < 48);
            int hc = min(max(hh, 0), 511), wl = min(max(ww, 0), 47);
            const unsigned short* src = gb + (((long)b * 512 + hc) * 48 + wl) * 64 + quad * 8;
            uint4 z = make_uint4(0, 0, 0, 0);
            ABu a0, a1;
            a0.q = ok ? *(const uint4*)src : z;
            a1.q = ok ? *(const uint4*)(src + 32) : z;
            acc = __builtin_amdgcn_mfma_f32_16x16x32_bf16(a0.bf, Bf[tap][0], acc, 0, 0, 0);
            acc = __builtin_amdgcn_mfma_f32_16x16x32_bf16(a1.bf, Bf[tap][1], acc, 0, 0, 0);
        }
        unsigned short* dst = cb + (((long)b * 512 + r) * 48 + w0) * 64 + tt * 16 + n;
#pragma unroll
        for (int r2 = 0; r2 < 4; r2++) {
            int m2 = quad * 4 + r2;      // pixel within segment
            dst[(long)m2 * 64] = f2bf(acc[r2]);
        }
    }
}

// ---- bilinear gather + GEMM3 via MFMA -> h3 row-major bf16 (conv in bf16) ----
__global__ __launch_bounds__(256, 2) void k_gather3_mfma(const unsigned short* __restrict__ h2b,
        const unsigned short* __restrict__ convb, const float* __restrict__ ab2,
        const float* __restrict__ abC, const float* __restrict__ cylidx,
        const float* __restrict__ pts, const float* __restrict__ w3,
        unsigned short* __restrict__ h3b, int N) {
    int lane = threadIdx.x & 63;
    int c = lane & 15, quad = lane >> 4;
    int wid = (blockIdx.x * 256 + threadIdx.x) >> 6;
    int nw = gridDim.x * 4;
    bf16x8_t Bf[4][4];
#pragma unroll
    for (int tt = 0; tt < 4; tt++)
#pragma unroll
        for (int kc = 0; kc < 4; kc++) {
            const float* wr = w3 + (tt * 16 + c) * 128 + kc * 32 + quad * 8;
            float4 w0 = *(const float4*)wr;
            float4 w1 = *(const float4*)(wr + 4);
            ABu tmp;
            tmp.us[0] = f2bf(w0.x); tmp.us[1] = f2bf(w0.y);
            tmp.us[2] = f2bf(w0.z); tmp.us[3] = f2bf(w0.w);
            tmp.us[4] = f2bf(w1.x); tmp.us[5] = f2bf(w1.y);
            tmp.us[6] = f2bf(w1.z); tmp.us[7] = f2bf(w1.w);
            Bf[tt][kc] = tmp.bf;
        }
    float a2[16], b2[16], aC[16], bC[16];
#pragma unroll
    for (int kc = 0; kc < 2; kc++)
#pragma unroll
        for (int j = 0; j < 8; j++) {
            int kk = kc * 32 + quad * 8 + j;
            a2[kc * 8 + j] = ab2[64 + kk];
            b2[kc * 8 + j] = ab2[192 + kk];
            aC[kc * 8 + j] = abC[kk];
            bC[kc * 8 + j] = abC[64 + kk];
        }
    int ntiles = (N + 15) >> 4;
    for (int tile = wid; tile < ntiles; tile += nw) {
        int p0 = tile * 16;
        int p = min(p0 + c, N - 1);
        float yq = cylidx[p * 2], xq = cylidx[p * 2 + 1];
        int b = (int)pts[p * 5];
        int xf = (int)floorf(xq), yf = (int)floorf(yq);
        int x0 = min(max(xf, 0), 47);
        int x1 = min(max(xf + 1, 0), 47);
        int y0 = min(max(yf, 0), 511);
        int y1 = min(max(yf + 1, 0), 511);
        float x0f = (float)x0, x1f = (float)x1, y0f = (float)y0, y1f = (float)y1;
        float wa = (x1f - xq) * (y1f - yq);
        float wb = (x1f - xq) * (yq - y0f);
        float wc2 = (xq - x0f) * (y1f - yq);
        float wd = (xq - x0f) * (yq - y0f);
        const unsigned short* Ia = convb + (((long)b * 512 + y0) * 48 + x0) * 64;
        const unsigned short* Ib = convb + (((long)b * 512 + y1) * 48 + x0) * 64;
        const unsigned short* Ic = convb + (((long)b * 512 + y0) * 48 + x1) * 64;
        const unsigned short* Id = convb + (((long)b * 512 + y1) * 48 + x1) * 64;
        bf16x8_t Af[4];
#pragma unroll
        for (int kc = 0; kc < 2; kc++) {
            ABu u;
            u.q = *(const uint4*)(h2b + (long)p * 128 + 64 + kc * 32 + quad * 8);
            ABu o;
#pragma unroll
            for (int j = 0; j < 8; j++)
                o.us[j] = f2bf(bnr(bf2f(u.us[j]), a2[kc * 8 + j], b2[kc * 8 + j]));
            Af[kc] = o.bf;
        }
#pragma unroll
        for (int kc = 0; kc < 2; kc++) {
            int cbo = kc * 32 + quad * 8;
            ABu ua, ub, uc, ud;
            ua.q = *(const uint4*)(Ia + cbo);
            ub.q = *(const uint4*)(Ib + cbo);
            uc.q = *(const uint4*)(Ic + cbo);
            ud.q = *(const uint4*)(Id + cbo);
            ABu o;
#pragma unroll
            for (int j = 0; j < 8; j++) {
                float aa = aC[kc * 8 + j], bbv = bC[kc * 8 + j];
                float v = wa * bnr(bf2f(ua.us[j]), aa, bbv) + wb * bnr(bf2f(ub.us[j]), aa, bbv)
                        + wc2 * bnr(bf2f(uc.us[j]), aa, bbv) + wd * bnr(bf2f(ud.us[j]), aa, bbv);
                o.us[j] = f2bf(v);
            }
            Af[2 + kc] = o.bf;
        }
        f32x4_t acc[4];
#pragma unroll
        for (int tt = 0; tt < 4; tt++) acc[tt] = (f32x4_t){0.f, 0.f, 0.f, 0.f};
#pragma unroll
        for (int tt = 0; tt < 4; tt++)
#pragma unroll
            for (int kc = 0; kc < 4; kc++)
                acc[tt] = __builtin_amdgcn_mfma_f32_16x16x32_bf16(Af[kc], Bf[tt][kc], acc[tt], 0, 0, 0);
#pragma unroll
        for (int tt = 0; tt < 4; tt++)
#pragma unroll
            for (int r = 0; r < 4; r++) {
                int pr = p0 + quad * 4 + r;
                if (pr < N) h3b[(long)pr * 64 + tt * 16 + c] = f2bf(acc[tt][r]);
            }
    }
}

// ---- final BN-ReLU -> out_fea fp32 + bev scatter-max; ONE WAVE PER POINT ----
__global__ __launch_bounds__(256) void k_out_tile3(const unsigned short* __restrict__ h3b,
        const float* __restrict__ ab3, const int* __restrict__ binv,
        float* __restrict__ out_fea, unsigned int* __restrict__ out_bev, int N) {
    int t = threadIdx.x, lane = t & 63, w = t >> 6;
    int p = blockIdx.x * 4 + w;
    if (p >= N) return;
    float a = ab3[lane], bb = ab3[64 + lane];
    float v = bnr(bf2f(h3b[(long)p * 64 + lane]), a, bb);
    out_fea[(long)p * 64 + lane] = v;
    int bi = binv[p];
    if (v > 0.f) {
        unsigned uv = __float_as_uint(v);
        unsigned* cell = out_bev + (long)bi * 64;
        unsigned cur = cell[lane];
        if (uv > cur) atomicMax(&cell[lane], uv);
    }
}

// ---- voxel coords ----
__global__ void k_voxcoords(const int* __restrict__ coords, float* __restrict__ out, int Nb) {
    int i = blockIdx.x * blockDim.x + threadIdx.x;
    if (i >= Nb) return;
    int c = coords[i];
    int vb = c / BEV_SXY;
    int rem = c % BEV_SXY;
    int vx = rem / BEV_SY;
    int vy = rem % BEV_SY;
    out[i * 4 + 0] = (float)vb;
    out[i * 4 + 1] = 0.f;
    out[i * 4 + 2] = (float)vy;
    out[i * 4 + 3] = (float)vx;
}

extern "C" void kernel_launch(void* const* d_in, const int* in_sizes, int n_in,
                              void* d_out, int out_size, void* d_ws, size_t ws_size,
                              hipStream_t stream) {
    const float* pts = (const float*)d_in[0];
    const float* pcyl = (const float*)d_in[1];
    const float* cylidx = (const float*)d_in[2];
    const float* bevidx = (const float*)d_in[3];
    const float* w1 = (const float*)d_in[4];
    const float* g1 = (const float*)d_in[5];
    const float* b1 = (const float*)d_in[6];
    const float* w2 = (const float*)d_in[7];
    const float* g2 = (const float*)d_in[8];
    const float* b2 = (const float*)d_in[9];
    const float* wc = (const float*)d_in[10];
    const float* gc = (const float*)d_in[11];
    const float* bc = (const float*)d_in[12];
    const float* w3 = (const float*)d_in[13];
    const float* g3 = (const float*)d_in[14];
    const float* b3 = (const float*)d_in[15];
    const int* binv = (const int*)d_in[16];
    const int* bcoords = (const int*)d_in[17];
    const int* cinv = (const int*)d_in[18];
    const int* ccoords = (const int*)d_in[19];
    int N = in_sizes[0] / 5;
    int Nb = in_sizes[17];
    int Nc = in_sizes[19];
    const int B = 4;
    const long GRIDSZ = (long)B * 512 * 48 * 64;

    char* wsb = (char*)d_ws;
    unsigned short* h2b = (unsigned short*)wsb;                     // 128N bf16
    unsigned short* h13b = (unsigned short*)(wsb + 256L * N);       // 64N bf16 (h1, then h3)
    float* grid = (float*)(wsb + 384L * N);                         // fp32 (atomics)
    unsigned short* gridb = (unsigned short*)(grid + GRIDSZ);       // bf16 conv input
    unsigned short* convb = gridb + GRIDSZ;                         // bf16 conv output
    float* bacc = (float*)(convb + GRIDSZ);
    float* cacc = bacc + 3L * Nb;
    float* stats = cacc + 3L * Nc;
    float* wct = stats + 1280;
    float* st1 = stats, *st2 = stats + 128, *st3 = stats + 384, *stC = stats + 512;
    float* ab1 = stats + 640, *ab2 = stats + 768, *ab3 = stats + 1024, *abC = stats + 1152;

    float* out_fea = (float*)d_out;
    unsigned int* out_bev = (unsigned int*)((float*)d_out + (long)N * 64);
    float* out_vc = (float*)d_out + (long)N * 64 + (long)Nb * 64;

    hipMemsetAsync(grid, 0, (size_t)GRIDSZ * 4, stream);
    hipMemsetAsync(bacc, 0, (size_t)3 * Nb * 4, stream);
    hipMemsetAsync(cacc, 0, (size_t)3 * Nc * 4, stream);
    hipMemsetAsync(stats, 0, 1280 * 4, stream);
    hipMemsetAsync(out_bev, 0, (size_t)Nb * 64 * 4, stream);

    int nb256 = (N + 255) / 256;
    k_wct<<<(9 * 64 * 64 + 255) / 256, 256, 0, stream>>>(wc, wct);
    k_scatter_sums<<<nb256, 256, 0, stream>>>(pts, pcyl, binv, cinv, bacc, cacc, N, Nb, Nc);
    k_feat_gemm1<<<nb256, 256, 0, stream>>>(pts, pcyl, cylidx, bevidx, binv, cinv, bacc, cacc, w1, h13b, N, Nb, Nc);
    k_stats_rm<<<512, 256, 0, stream>>>(h13b, 64L * N, 64, st1);
    k_finalize<<<1, 128, 0, stream>>>(st1, g1, b1, ab1, 64, 1.0f / (float)N);
    k_gemm2_mfma<<<512, 256, 0, stream>>>(h13b, w2, ab1, h2b, N);
    k_stats_rm<<<512, 256, 0, stream>>>(h2b, 128L * N, 128, st2);
    k_finalize<<<1, 128, 0, stream>>>(st2, g2, b2, ab2, 128, 1.0f / (float)N);
    k_cylmax4<<<(N + 3) / 4, 256, 0, stream>>>(h2b, ab2, pts, cylidx, (unsigned int*)grid, N);
    k_g2b<<<(int)((GRIDSZ / 8 + 255) / 256), 256, 0, stream>>>(grid, gridb, GRIDSZ);
    k_conv_mfma<<<1536, 256, 0, stream>>>(gridb, wct, convb);
    k_stats_rm<<<512, 256, 0, stream>>>(convb, GRIDSZ, 64, stC);
    k_finalize<<<1, 128, 0, stream>>>(stC, gc, bc, abC, 64, 1.0f / (float)(B * 512 * 48));
    k_gather3_mfma<<<512, 256, 0, stream>>>(h2b, convb, ab2, abC, cylidx, pts, w3, h13b, N);
    k_stats_rm<<<512, 256, 0, stream>>>(h13b, 64L * N, 64, st3);
    k_finalize<<<1, 128, 0, stream>>>(st3, g3, b3, ab3, 64, 1.0f / (float)N);
    k_out_tile3<<<(N + 3) / 4, 256, 0, stream>>>(h13b, ab3, binv, out_fea, out_bev, N);
    k_voxcoords<<<(Nb + 255) / 256, 256, 0, stream>>>(bcoords, out_vc, Nb);
}

// Round 5
// 633.342 us; speedup vs baseline: 2.5409x; 1.0445x over previous
//
#include <hip/hip_runtime.h>
#include <math.h>

#define BN_EPS 1e-3f

static constexpr float CR0 = -3.14159265f;
static constexpr float CR1 = -2.0f;
static constexpr float CVS0 = (float)((3.14159265 * 2.0) / 512.0);
static constexpr float CVS1 = (float)(6.0 / 48.0);
#define BEV_SXY (220 * 250)
#define BEV_SY 250

typedef __attribute__((ext_vector_type(8))) __bf16 bf16x8_t;
typedef __attribute__((ext_vector_type(4))) float f32x4_t;

union ABu { uint4 q; unsigned short us[8]; bf16x8_t bf; };

__device__ __forceinline__ float bnr(float x, float a, float b) {
    float v = fmaf(x, a, b);
    return v > 0.f ? v : 0.f;
}
__device__ __forceinline__ float bf2f(unsigned short u) {
    return __uint_as_float(((unsigned)u) << 16);
}
__device__ __forceinline__ unsigned short f2bf(float f) {
    unsigned u = __float_as_uint(f);
    u += 0x7FFFu + ((u >> 16) & 1u);
    return (unsigned short)(u >> 16);
}
// BN coefs from raw sums: a = g*rsqrt(var+eps), b = beta - mean*a
__device__ __forceinline__ void bn_ab(const float* st, const float* g, const float* b,
                                      int C, int ch, float invn, float& a, float& bb) {
    float m = st[ch] * invn;
    float var = st[C + ch] * invn - m * m;
    a = g[ch] * rsqrtf(var + BN_EPS);
    bb = b[ch] - m * a;
}

// ---- segment sums for means + conv-weight pre-pack (wctb bf16 fragment layout) ----
// wctb[tap<<12 | kc<<11 | quad<<9 | oc<<3 | j] = bf16(wc[oc][kc*32+quad*8+j][tap/3][tap%3])
__global__ void k_scatter_sums(const float* __restrict__ pts, const float* __restrict__ pcyl,
                               const int* __restrict__ binv, const int* __restrict__ cinv,
                               const float* __restrict__ wc, unsigned short* __restrict__ wctb,
                               float* __restrict__ bacc, float* __restrict__ cacc,
                               int N, int Nb, int Nc) {
    int p = blockIdx.x * blockDim.x + threadIdx.x;
    if (p < 9 * 4096) {
        int j = p & 7, oc = (p >> 3) & 63, quad = (p >> 9) & 3, kc = (p >> 11) & 1, tap = p >> 12;
        int ic = kc * 32 + quad * 8 + j;
        wctb[p] = f2bf(wc[((oc * 64 + ic) * 3 + tap / 3) * 3 + tap % 3]);
    }
    if (p >= N) return;
    float x = pts[p * 5 + 1], y = pts[p * 5 + 2];
    float ph = pcyl[p * 3 + 0], z = pcyl[p * 3 + 1];
    int bi = binv[p], ci = cinv[p];
    atomicAdd(&bacc[bi], 1.0f);
    atomicAdd(&bacc[Nb + bi], x);
    atomicAdd(&bacc[2 * Nb + bi], y);
    atomicAdd(&cacc[ci], 1.0f);
    atomicAdd(&cacc[Nc + ci], ph);
    atomicAdd(&cacc[2 * Nc + ci], z);
}

// ---- 16-feat build + GEMM1 (16->64), h1 row-major bf16 via LDS transpose ----
__global__ __launch_bounds__(256) void k_feat_gemm1(const float* __restrict__ pts,
        const float* __restrict__ pcyl, const float* __restrict__ cylidx,
        const float* __restrict__ bevidx, const int* __restrict__ binv,
        const int* __restrict__ cinv, const float* __restrict__ bacc,
        const float* __restrict__ cacc, const float* __restrict__ w1,
        unsigned short* __restrict__ h1b, int N, int Nb, int Nc) {
    __shared__ float w1s[1024];
    __shared__ unsigned int tbuf[32 * 260];
    int t = threadIdx.x;
    for (int i = t; i < 1024; i += 256) w1s[i] = w1[i];
    __syncthreads();
    int p = blockIdx.x * 256 + t;
    int pc = min(p, N - 1);
    float x = pts[pc * 5 + 1], y = pts[pc * 5 + 2], z = pts[pc * 5 + 3], inten = pts[pc * 5 + 4];
    float ph = pcyl[pc * 3 + 0], zc = pcyl[pc * 3 + 1], rho = pcyl[pc * 3 + 2];
    float ci0 = cylidx[pc * 2 + 0], ci1 = cylidx[pc * 2 + 1];
    float bi0 = bevidx[pc * 2 + 0], bi1 = bevidx[pc * 2 + 1];
    float bc0 = floorf(bi0), bc1 = floorf(bi1);
    float cc0 = floorf(ci0), cc1 = floorf(ci1);
    int bv = binv[pc], cv = cinv[pc];
    float bcnt = bacc[bv];
    float bmx = bacc[Nb + bv] / bcnt, bmy = bacc[2 * Nb + bv] / bcnt;
    float ccnt = cacc[cv];
    float cmp = cacc[Nc + cv] / ccnt, cmz = cacc[2 * Nc + cv] / ccnt;
    float f[16];
    f[0] = x; f[1] = y; f[2] = z;
    f[3] = ph; f[4] = zc; f[5] = rho;
    f[6] = x - ((bc0 + 0.5f) * 0.32f + 0.0f);
    f[7] = y - ((bc1 + 0.5f) * 0.32f + (-40.0f));
    f[8] = ph - ((cc0 + 0.5f) * CVS0 + CR0);
    f[9] = zc - ((cc1 + 0.5f) * CVS1 + CR1);
    f[10] = x - bmx; f[11] = y - bmy;
    f[12] = ph - cmp; f[13] = zc - cmz;
    f[14] = sqrtf(x * x + y * y + z * z);
    f[15] = inten;
    for (int c2 = 0; c2 < 32; c2++) {
        float s0 = 0.f, s1 = 0.f;
        const float* w0 = &w1s[(2 * c2) * 16];
        const float* w1p = &w1s[(2 * c2 + 1) * 16];
#pragma unroll
        for (int k = 0; k < 16; k++) {
            s0 = fmaf(f[k], w0[k], s0);
            s1 = fmaf(f[k], w1p[k], s1);
        }
        tbuf[c2 * 260 + t] = (unsigned)f2bf(s0) | ((unsigned)f2bf(s1) << 16);
    }
    __syncthreads();
#pragma unroll
    for (int r = 0; r < 4; r++) {
        int cid = t + 256 * r;
        int pp = cid >> 2;
        int gp = blockIdx.x * 256 + pp;
        if (gp < N) {
            int c2b = (cid & 3) * 8;
            uint4 A, Bv;
            A.x = tbuf[(c2b + 0) * 260 + pp];
            A.y = tbuf[(c2b + 1) * 260 + pp];
            A.z = tbuf[(c2b + 2) * 260 + pp];
            A.w = tbuf[(c2b + 3) * 260 + pp];
            Bv.x = tbuf[(c2b + 4) * 260 + pp];
            Bv.y = tbuf[(c2b + 5) * 260 + pp];
            Bv.z = tbuf[(c2b + 6) * 260 + pp];
            Bv.w = tbuf[(c2b + 7) * 260 + pp];
            uint4* dst = (uint4*)(h1b + (long)gp * 64 + (cid & 3) * 16);
            dst[0] = A;
            dst[1] = Bv;
        }
    }
}

// ---- stats over row-major bf16 buffer (channel = index % C) ----
__global__ void k_stats_rm(const unsigned short* __restrict__ buf, long T, int C,
                           float* __restrict__ out) {
    int t = threadIdx.x;
    long g = (long)blockIdx.x * 256 + t;
    long stride = (long)gridDim.x * 256;
    float s = 0.f, q = 0.f;
    for (long i = g; i < T; i += stride) {
        float v = bf2f(buf[i]);
        s += v;
        q = fmaf(v, v, q);
    }
    __shared__ float ls[256], lq[256];
    ls[t] = s; lq[t] = q;
    __syncthreads();
    if (t < C) {
        for (int o = t + C; o < 256; o += C) { s += ls[o]; q += lq[o]; }
        atomicAdd(&out[t], s);
        atomicAdd(&out[C + t], q);
    }
}

// ---- GEMM2 via MFMA (BN1 coefs computed inline from st1) ----
__global__ __launch_bounds__(256, 2) void k_gemm2_mfma(const unsigned short* __restrict__ h1b,
        const float* __restrict__ w2, const float* __restrict__ st1,
        const float* __restrict__ g1, const float* __restrict__ b1g, float invn,
        unsigned short* __restrict__ h2b, int N) {
    int lane = threadIdx.x & 63;
    int c = lane & 15, quad = lane >> 4;
    int wid = (blockIdx.x * 256 + threadIdx.x) >> 6;
    int nw = gridDim.x * 4;
    bf16x8_t Bf[8][2];
#pragma unroll
    for (int tt = 0; tt < 8; tt++)
#pragma unroll
        for (int kc = 0; kc < 2; kc++) {
            const float* wr = w2 + (tt * 16 + c) * 64 + kc * 32 + quad * 8;
            float4 w0 = *(const float4*)wr;
            float4 w1 = *(const float4*)(wr + 4);
            ABu tmp;
            tmp.us[0] = f2bf(w0.x); tmp.us[1] = f2bf(w0.y);
            tmp.us[2] = f2bf(w0.z); tmp.us[3] = f2bf(w0.w);
            tmp.us[4] = f2bf(w1.x); tmp.us[5] = f2bf(w1.y);
            tmp.us[6] = f2bf(w1.z); tmp.us[7] = f2bf(w1.w);
            Bf[tt][kc] = tmp.bf;
        }
    float a1[16], b1[16];
#pragma unroll
    for (int kc = 0; kc < 2; kc++)
#pragma unroll
        for (int j = 0; j < 8; j++) {
            int ch = kc * 32 + quad * 8 + j;
            bn_ab(st1, g1, b1g, 64, ch, invn, a1[kc * 8 + j], b1[kc * 8 + j]);
        }
    int ntiles = (N + 15) >> 4;
    for (int tile = wid; tile < ntiles; tile += nw) {
        int p0 = tile * 16;
        int pa = min(p0 + c, N - 1);
        bf16x8_t Af[2];
#pragma unroll
        for (int kc = 0; kc < 2; kc++) {
            ABu u;
            u.q = *(const uint4*)(h1b + (long)pa * 64 + kc * 32 + quad * 8);
            ABu o;
#pragma unroll
            for (int j = 0; j < 8; j++)
                o.us[j] = f2bf(bnr(bf2f(u.us[j]), a1[kc * 8 + j], b1[kc * 8 + j]));
            Af[kc] = o.bf;
        }
        f32x4_t acc[8];
#pragma unroll
        for (int tt = 0; tt < 8; tt++) acc[tt] = (f32x4_t){0.f, 0.f, 0.f, 0.f};
#pragma unroll
        for (int tt = 0; tt < 8; tt++) {
            acc[tt] = __builtin_amdgcn_mfma_f32_16x16x32_bf16(Af[0], Bf[tt][0], acc[tt], 0, 0, 0);
            acc[tt] = __builtin_amdgcn_mfma_f32_16x16x32_bf16(Af[1], Bf[tt][1], acc[tt], 0, 0, 0);
        }
#pragma unroll
        for (int tt = 0; tt < 8; tt++)
#pragma unroll
            for (int r = 0; r < 4; r++) {
                int pr = p0 + quad * 4 + r;
                if (pr < N) h2b[(long)pr * 128 + tt * 16 + c] = f2bf(acc[tt][r]);
            }
    }
}

// ---- scatter-max into dense cyl grid; one wave per point (lane = channel) ----
__global__ __launch_bounds__(256) void k_cylmax4(const unsigned short* __restrict__ h2b,
        const float* __restrict__ st2, const float* __restrict__ g2,
        const float* __restrict__ b2g, float invn, const float* __restrict__ pts,
        const float* __restrict__ cylidx, unsigned int* __restrict__ grid, int N) {
    int t = threadIdx.x, lane = t & 63, w = t >> 6;
    int p = blockIdx.x * 4 + w;
    if (p >= N) return;
    float a, bb;
    bn_ab(st2, g2, b2g, 128, lane, invn, a, bb);
    float v = bnr(bf2f(h2b[(long)p * 128 + lane]), a, bb);
    int b = (int)pts[p * 5];
    int cx = (int)floorf(cylidx[p * 2]);
    int cy = (int)floorf(cylidx[p * 2 + 1]);
    unsigned int* cell = grid + (((long)b * 512 + cx) * 48 + cy) * 64;
    if (v > 0.f) {
        unsigned uv = __float_as_uint(v);
        unsigned cur = cell[lane];
        if (uv > cur) atomicMax(&cell[lane], uv);
    }
}

// ---- fp32 grid -> bf16 grid ----
__global__ void k_g2b(const float* __restrict__ g, unsigned short* __restrict__ gb, long T) {
    long i = ((long)blockIdx.x * 256 + threadIdx.x) * 8;
    if (i >= T) return;
    float4 a = *(const float4*)(g + i);
    float4 b = *(const float4*)(g + i + 4);
    ABu o;
    o.us[0] = f2bf(a.x); o.us[1] = f2bf(a.y); o.us[2] = f2bf(a.z); o.us[3] = f2bf(a.w);
    o.us[4] = f2bf(b.x); o.us[5] = f2bf(b.y); o.us[6] = f2bf(b.z); o.us[7] = f2bf(b.w);
    *(uint4*)(gb + i) = o.q;
}

// ---- 3x3 conv as implicit-GEMM MFMA; pre-packed bf16 weights; 1 tile/wave; 2 acc chains ----
__global__ __launch_bounds__(256) void k_conv_mfma2(const unsigned short* __restrict__ gb,
        const unsigned short* __restrict__ wctb, unsigned short* __restrict__ cb) {
    int lane = threadIdx.x & 63;
    int n = lane & 15, quad = lane >> 4;
    int wid = blockIdx.x * 4 + (threadIdx.x >> 6);   // 0..24575
    int tt = wid & 3;
    int rem = wid >> 2;
    int seg = rem % 3;
    int rr = rem / 3;
    int r = rr & 511;
    int b = rr >> 9;
    int w0 = seg * 16;
    const unsigned short* wb = wctb + quad * 512 + (tt * 16 + n) * 8;
    f32x4_t acc0 = (f32x4_t){0.f, 0.f, 0.f, 0.f};
    f32x4_t acc1 = (f32x4_t){0.f, 0.f, 0.f, 0.f};
#pragma unroll
    for (int tap = 0; tap < 9; tap++) {
        int dh = tap / 3 - 1, dw = tap % 3 - 1;
        int hh = r + dh, ww = w0 + n + dw;
        bool ok = (hh >= 0) && (hh < 512) && (ww >= 0) && (ww < 48);
        int hc = min(max(hh, 0), 511), wl = min(max(ww, 0), 47);
        const unsigned short* src = gb + (((long)b * 512 + hc) * 48 + wl) * 64 + quad * 8;
        uint4 z = make_uint4(0, 0, 0, 0);
        ABu a0, a1, b0, b1;
        a0.q = ok ? *(const uint4*)src : z;
        a1.q = ok ? *(const uint4*)(src + 32) : z;
        b0.q = *(const uint4*)(wb + (tap * 2 + 0) * 2048);
        b1.q = *(const uint4*)(wb + (tap * 2 + 1) * 2048);
        acc0 = __builtin_amdgcn_mfma_f32_16x16x32_bf16(a0.bf, b0.bf, acc0, 0, 0, 0);
        acc1 = __builtin_amdgcn_mfma_f32_16x16x32_bf16(a1.bf, b1.bf, acc1, 0, 0, 0);
    }
    unsigned short* dst = cb + (((long)b * 512 + r) * 48 + w0) * 64 + tt * 16 + n;
#pragma unroll
    for (int r2 = 0; r2 < 4; r2++) {
        int m2 = quad * 4 + r2;
        dst[(long)m2 * 64] = f2bf(acc0[r2] + acc1[r2]);
    }
}

// ---- bilinear gather + GEMM3 via MFMA -> h3 row-major bf16 (BN coefs inline) ----
__global__ __launch_bounds__(256, 2) void k_gather3_mfma(const unsigned short* __restrict__ h2b,
        const unsigned short* __restrict__ convb, const float* __restrict__ st2,
        const float* __restrict__ g2, const float* __restrict__ b2g,
        const float* __restrict__ stC, const float* __restrict__ gc,
        const float* __restrict__ bcg, float invn, float invnC,
        const float* __restrict__ cylidx, const float* __restrict__ pts,
        const float* __restrict__ w3, unsigned short* __restrict__ h3b, int N) {
    int lane = threadIdx.x & 63;
    int c = lane & 15, quad = lane >> 4;
    int wid = (blockIdx.x * 256 + threadIdx.x) >> 6;
    int nw = gridDim.x * 4;
    bf16x8_t Bf[4][4];
#pragma unroll
    for (int tt = 0; tt < 4; tt++)
#pragma unroll
        for (int kc = 0; kc < 4; kc++) {
            const float* wr = w3 + (tt * 16 + c) * 128 + kc * 32 + quad * 8;
            float4 w0 = *(const float4*)wr;
            float4 w1 = *(const float4*)(wr + 4);
            ABu tmp;
            tmp.us[0] = f2bf(w0.x); tmp.us[1] = f2bf(w0.y);
            tmp.us[2] = f2bf(w0.z); tmp.us[3] = f2bf(w0.w);
            tmp.us[4] = f2bf(w1.x); tmp.us[5] = f2bf(w1.y);
            tmp.us[6] = f2bf(w1.z); tmp.us[7] = f2bf(w1.w);
            Bf[tt][kc] = tmp.bf;
        }
    float a2[16], b2[16], aC[16], bC[16];
#pragma unroll
    for (int kc = 0; kc < 2; kc++)
#pragma unroll
        for (int j = 0; j < 8; j++) {
            int kk = kc * 32 + quad * 8 + j;
            bn_ab(st2, g2, b2g, 128, 64 + kk, invn, a2[kc * 8 + j], b2[kc * 8 + j]);
            bn_ab(stC, gc, bcg, 64, kk, invnC, aC[kc * 8 + j], bC[kc * 8 + j]);
        }
    int ntiles = (N + 15) >> 4;
    for (int tile = wid; tile < ntiles; tile += nw) {
        int p0 = tile * 16;
        int p = min(p0 + c, N - 1);
        float yq = cylidx[p * 2], xq = cylidx[p * 2 + 1];
        int b = (int)pts[p * 5];
        int xf = (int)floorf(xq), yf = (int)floorf(yq);
        int x0 = min(max(xf, 0), 47);
        int x1 = min(max(xf + 1, 0), 47);
        int y0 = min(max(yf, 0), 511);
        int y1 = min(max(yf + 1, 0), 511);
        float x0f = (float)x0, x1f = (float)x1, y0f = (float)y0, y1f = (float)y1;
        float wa = (x1f - xq) * (y1f - yq);
        float wb = (x1f - xq) * (yq - y0f);
        float wc2 = (xq - x0f) * (y1f - yq);
        float wd = (xq - x0f) * (yq - y0f);
        const unsigned short* Ia = convb + (((long)b * 512 + y0) * 48 + x0) * 64;
        const unsigned short* Ib = convb + (((long)b * 512 + y1) * 48 + x0) * 64;
        const unsigned short* Ic = convb + (((long)b * 512 + y0) * 48 + x1) * 64;
        const unsigned short* Id = convb + (((long)b * 512 + y1) * 48 + x1) * 64;
        bf16x8_t Af[4];
#pragma unroll
        for (int kc = 0; kc < 2; kc++) {
            ABu u;
            u.q = *(const uint4*)(h2b + (long)p * 128 + 64 + kc * 32 + quad * 8);
            ABu o;
#pragma unroll
            for (int j = 0; j < 8; j++)
                o.us[j] = f2bf(bnr(bf2f(u.us[j]), a2[kc * 8 + j], b2[kc * 8 + j]));
            Af[kc] = o.bf;
        }
#pragma unroll
        for (int kc = 0; kc < 2; kc++) {
            int cbo = kc * 32 + quad * 8;
            ABu ua, ub, uc, ud;
            ua.q = *(const uint4*)(Ia + cbo);
            ub.q = *(const uint4*)(Ib + cbo);
            uc.q = *(const uint4*)(Ic + cbo);
            ud.q = *(const uint4*)(Id + cbo);
            ABu o;
#pragma unroll
            for (int j = 0; j < 8; j++) {
                float aa = aC[kc * 8 + j], bbv = bC[kc * 8 + j];
                float v = wa * bnr(bf2f(ua.us[j]), aa, bbv) + wb * bnr(bf2f(ub.us[j]), aa, bbv)
                        + wc2 * bnr(bf2f(uc.us[j]), aa, bbv) + wd * bnr(bf2f(ud.us[j]), aa, bbv);
                o.us[j] = f2bf(v);
            }
            Af[2 + kc] = o.bf;
        }
        f32x4_t acc[4];
#pragma unroll
        for (int tt = 0; tt < 4; tt++) acc[tt] = (f32x4_t){0.f, 0.f, 0.f, 0.f};
#pragma unroll
        for (int tt = 0; tt < 4; tt++)
#pragma unroll
            for (int kc = 0; kc < 4; kc++)
                acc[tt] = __builtin_amdgcn_mfma_f32_16x16x32_bf16(Af[kc], Bf[tt][kc], acc[tt], 0, 0, 0);
#pragma unroll
        for (int tt = 0; tt < 4; tt++)
#pragma unroll
            for (int r = 0; r < 4; r++) {
                int pr = p0 + quad * 4 + r;
                if (pr < N) h3b[(long)pr * 64 + tt * 16 + c] = f2bf(acc[tt][r]);
            }
    }
}

// ---- final BN-ReLU -> out_fea fp32 + bev scatter-max + voxel coords ----
__global__ __launch_bounds__(256) void k_out_tile3(const unsigned short* __restrict__ h3b,
        const float* __restrict__ st3, const float* __restrict__ g3,
        const float* __restrict__ b3g, float invn, const int* __restrict__ binv,
        float* __restrict__ out_fea, unsigned int* __restrict__ out_bev,
        const int* __restrict__ bcoords, float* __restrict__ out_vc, int Nb, int N) {
    int t = threadIdx.x, lane = t & 63, w = t >> 6;
    long gid = (long)blockIdx.x * 256 + t;
    if (gid < Nb) {
        int cc = bcoords[gid];
        int vb = cc / BEV_SXY;
        int rem = cc % BEV_SXY;
        int vx = rem / BEV_SY;
        int vy = rem % BEV_SY;
        out_vc[gid * 4 + 0] = (float)vb;
        out_vc[gid * 4 + 1] = 0.f;
        out_vc[gid * 4 + 2] = (float)vy;
        out_vc[gid * 4 + 3] = (float)vx;
    }
    int p = blockIdx.x * 4 + w;
    if (p >= N) return;
    float a, bb;
    bn_ab(st3, g3, b3g, 64, lane, invn, a, bb);
    float v = bnr(bf2f(h3b[(long)p * 64 + lane]), a, bb);
    out_fea[(long)p * 64 + lane] = v;
    int bi = binv[p];
    if (v > 0.f) {
        unsigned uv = __float_as_uint(v);
        unsigned* cell = out_bev + (long)bi * 64;
        unsigned cur = cell[lane];
        if (uv > cur) atomicMax(&cell[lane], uv);
    }
}

extern "C" void kernel_launch(void* const* d_in, const int* in_sizes, int n_in,
                              void* d_out, int out_size, void* d_ws, size_t ws_size,
                              hipStream_t stream) {
    const float* pts = (const float*)d_in[0];
    const float* pcyl = (const float*)d_in[1];
    const float* cylidx = (const float*)d_in[2];
    const float* bevidx = (const float*)d_in[3];
    const float* w1 = (const float*)d_in[4];
    const float* g1 = (const float*)d_in[5];
    const float* b1 = (const float*)d_in[6];
    const float* w2 = (const float*)d_in[7];
    const float* g2 = (const float*)d_in[8];
    const float* b2 = (const float*)d_in[9];
    const float* wc = (const float*)d_in[10];
    const float* gc = (const float*)d_in[11];
    const float* bc = (const float*)d_in[12];
    const float* w3 = (const float*)d_in[13];
    const float* g3 = (const float*)d_in[14];
    const float* b3 = (const float*)d_in[15];
    const int* binv = (const int*)d_in[16];
    const int* bcoords = (const int*)d_in[17];
    const int* cinv = (const int*)d_in[18];
    const int* ccoords = (const int*)d_in[19];
    int N = in_sizes[0] / 5;
    int Nb = in_sizes[17];
    int Nc = in_sizes[19];
    const int B = 4;
    const long GRIDSZ = (long)B * 512 * 48 * 64;
    float invN = 1.0f / (float)N;
    float invC = 1.0f / (float)(B * 512 * 48);

    char* wsb = (char*)d_ws;
    unsigned short* wctb = (unsigned short*)wsb;                  // 36864 bf16 = 73728 B
    unsigned short* h2b = (unsigned short*)(wsb + 73728);         // 128N bf16
    unsigned short* h13b = (unsigned short*)(wsb + 73728 + 256L * N); // 64N bf16
    float* grid = (float*)(wsb + 73728 + 384L * N);               // fp32 (atomics)
    unsigned short* gridb = (unsigned short*)(grid + GRIDSZ);     // bf16 conv input
    unsigned short* convb = gridb + GRIDSZ;                       // bf16 conv output
    float* bacc = (float*)(convb + GRIDSZ);
    float* cacc = bacc + 3L * Nb;
    float* stats = cacc + 3L * Nc;                                // 768 floats
    float* st1 = stats, *st2 = stats + 128, *st3 = stats + 384, *stC = stats + 512;

    float* out_fea = (float*)d_out;
    unsigned int* out_bev = (unsigned int*)((float*)d_out + (long)N * 64);
    float* out_vc = (float*)d_out + (long)N * 64 + (long)Nb * 64;

    hipMemsetAsync(grid, 0, (size_t)GRIDSZ * 4, stream);
    hipMemsetAsync(bacc, 0, (size_t)(3L * Nb + 3L * Nc + 768) * 4, stream);
    hipMemsetAsync(out_bev, 0, (size_t)Nb * 64 * 4, stream);

    int nb256 = (N + 255) / 256;
    k_scatter_sums<<<nb256, 256, 0, stream>>>(pts, pcyl, binv, cinv, wc, wctb, bacc, cacc, N, Nb, Nc);
    k_feat_gemm1<<<nb256, 256, 0, stream>>>(pts, pcyl, cylidx, bevidx, binv, cinv, bacc, cacc, w1, h13b, N, Nb, Nc);
    k_stats_rm<<<512, 256, 0, stream>>>(h13b, 64L * N, 64, st1);
    k_gemm2_mfma<<<512, 256, 0, stream>>>(h13b, w2, st1, g1, b1, invN, h2b, N);
    k_stats_rm<<<512, 256, 0, stream>>>(h2b, 128L * N, 128, st2);
    k_cylmax4<<<(N + 3) / 4, 256, 0, stream>>>(h2b, st2, g2, b2, invN, pts, cylidx, (unsigned int*)grid, N);
    k_g2b<<<(int)((GRIDSZ / 8 + 255) / 256), 256, 0, stream>>>(grid, gridb, GRIDSZ);
    k_conv_mfma2<<<6144, 256, 0, stream>>>(gridb, wctb, convb);
    k_stats_rm<<<512, 256, 0, stream>>>(convb, GRIDSZ, 64, stC);
    k_gather3_mfma<<<512, 256, 0, stream>>>(h2b, convb, st2, g2, b2, stC, gc, bc, invN, invC, cylidx, pts, w3, h13b, N);
    k_stats_rm<<<512, 256, 0, stream>>>(h13b, 64L * N, 64, st3);
    k_out_tile3<<<(N + 3) / 4, 256, 0, stream>>>(h13b, st3, g3, b3, invN, binv, out_fea, out_bev, bcoords, out_vc, Nb, N);
}

// Round 6
// 488.305 us; speedup vs baseline: 3.2956x; 1.2970x over previous
//
#include <hip/hip_runtime.h>
#include <math.h>

#define BN_EPS 1e-3f

static constexpr float CR0 = -3.14159265f;
static constexpr float CR1 = -2.0f;
static constexpr float CVS0 = (float)((3.14159265 * 2.0) / 512.0);
static constexpr float CVS1 = (float)(6.0 / 48.0);
#define BEV_SXY (220 * 250)
#define BEV_SY 250

typedef __attribute__((ext_vector_type(8))) __bf16 bf16x8_t;
typedef __attribute__((ext_vector_type(4))) float f32x4_t;

union ABu { uint4 q; unsigned short us[8]; bf16x8_t bf; };

__device__ __forceinline__ float bnr(float x, float a, float b) {
    float v = fmaf(x, a, b);
    return v > 0.f ? v : 0.f;
}
__device__ __forceinline__ float bf2f(unsigned short u) {
    return __uint_as_float(((unsigned)u) << 16);
}
__device__ __forceinline__ unsigned short f2bf(float f) {
    unsigned u = __float_as_uint(f);
    u += 0x7FFFu + ((u >> 16) & 1u);
    return (unsigned short)(u >> 16);
}
__device__ __forceinline__ void bn_ab(const float* st, const float* g, const float* b,
                                      int C, int ch, float invn, float& a, float& bb) {
    float m = st[ch] * invn;
    float var = st[C + ch] * invn - m * m;
    a = g[ch] * rsqrtf(var + BN_EPS);
    bb = b[ch] - m * a;
}

// ---- segment sums for means + conv-weight pre-pack (wctb bf16 fragment layout) ----
__global__ void k_scatter_sums(const float* __restrict__ pts, const float* __restrict__ pcyl,
                               const int* __restrict__ binv, const int* __restrict__ cinv,
                               const float* __restrict__ wc, unsigned short* __restrict__ wctb,
                               float* __restrict__ bacc, float* __restrict__ cacc,
                               int N, int Nb, int Nc) {
    int p = blockIdx.x * blockDim.x + threadIdx.x;
    if (p < 9 * 4096) {
        int j = p & 7, oc = (p >> 3) & 63, quad = (p >> 9) & 3, kc = (p >> 11) & 1, tap = p >> 12;
        int ic = kc * 32 + quad * 8 + j;
        wctb[p] = f2bf(wc[((oc * 64 + ic) * 3 + tap / 3) * 3 + tap % 3]);
    }
    if (p >= N) return;
    float x = pts[p * 5 + 1], y = pts[p * 5 + 2];
    float ph = pcyl[p * 3 + 0], z = pcyl[p * 3 + 1];
    int bi = binv[p], ci = cinv[p];
    atomicAdd(&bacc[bi], 1.0f);
    atomicAdd(&bacc[Nb + bi], x);
    atomicAdd(&bacc[2 * Nb + bi], y);
    atomicAdd(&cacc[ci], 1.0f);
    atomicAdd(&cacc[Nc + ci], ph);
    atomicAdd(&cacc[2 * Nc + ci], z);
}

// ---- 16-feat build + GEMM1 (16->64), h1 row-major bf16 via LDS transpose ----
__global__ __launch_bounds__(256) void k_feat_gemm1(const float* __restrict__ pts,
        const float* __restrict__ pcyl, const float* __restrict__ cylidx,
        const float* __restrict__ bevidx, const int* __restrict__ binv,
        const int* __restrict__ cinv, const float* __restrict__ bacc,
        const float* __restrict__ cacc, const float* __restrict__ w1,
        unsigned short* __restrict__ h1b, int N, int Nb, int Nc) {
    __shared__ float w1s[1024];
    __shared__ unsigned int tbuf[32 * 260];
    int t = threadIdx.x;
    for (int i = t; i < 1024; i += 256) w1s[i] = w1[i];
    __syncthreads();
    int p = blockIdx.x * 256 + t;
    int pc = min(p, N - 1);
    float x = pts[pc * 5 + 1], y = pts[pc * 5 + 2], z = pts[pc * 5 + 3], inten = pts[pc * 5 + 4];
    float ph = pcyl[pc * 3 + 0], zc = pcyl[pc * 3 + 1], rho = pcyl[pc * 3 + 2];
    float ci0 = cylidx[pc * 2 + 0], ci1 = cylidx[pc * 2 + 1];
    float bi0 = bevidx[pc * 2 + 0], bi1 = bevidx[pc * 2 + 1];
    float bc0 = floorf(bi0), bc1 = floorf(bi1);
    float cc0 = floorf(ci0), cc1 = floorf(ci1);
    int bv = binv[pc], cv = cinv[pc];
    float bcnt = bacc[bv];
    float bmx = bacc[Nb + bv] / bcnt, bmy = bacc[2 * Nb + bv] / bcnt;
    float ccnt = cacc[cv];
    float cmp = cacc[Nc + cv] / ccnt, cmz = cacc[2 * Nc + cv] / ccnt;
    float f[16];
    f[0] = x; f[1] = y; f[2] = z;
    f[3] = ph; f[4] = zc; f[5] = rho;
    f[6] = x - ((bc0 + 0.5f) * 0.32f + 0.0f);
    f[7] = y - ((bc1 + 0.5f) * 0.32f + (-40.0f));
    f[8] = ph - ((cc0 + 0.5f) * CVS0 + CR0);
    f[9] = zc - ((cc1 + 0.5f) * CVS1 + CR1);
    f[10] = x - bmx; f[11] = y - bmy;
    f[12] = ph - cmp; f[13] = zc - cmz;
    f[14] = sqrtf(x * x + y * y + z * z);
    f[15] = inten;
    for (int c2 = 0; c2 < 32; c2++) {
        float s0 = 0.f, s1 = 0.f;
        const float* w0 = &w1s[(2 * c2) * 16];
        const float* w1p = &w1s[(2 * c2 + 1) * 16];
#pragma unroll
        for (int k = 0; k < 16; k++) {
            s0 = fmaf(f[k], w0[k], s0);
            s1 = fmaf(f[k], w1p[k], s1);
        }
        tbuf[c2 * 260 + t] = (unsigned)f2bf(s0) | ((unsigned)f2bf(s1) << 16);
    }
    __syncthreads();
#pragma unroll
    for (int r = 0; r < 4; r++) {
        int cid = t + 256 * r;
        int pp = cid >> 2;
        int gp = blockIdx.x * 256 + pp;
        if (gp < N) {
            int c2b = (cid & 3) * 8;
            uint4 A, Bv;
            A.x = tbuf[(c2b + 0) * 260 + pp];
            A.y = tbuf[(c2b + 1) * 260 + pp];
            A.z = tbuf[(c2b + 2) * 260 + pp];
            A.w = tbuf[(c2b + 3) * 260 + pp];
            Bv.x = tbuf[(c2b + 4) * 260 + pp];
            Bv.y = tbuf[(c2b + 5) * 260 + pp];
            Bv.z = tbuf[(c2b + 6) * 260 + pp];
            Bv.w = tbuf[(c2b + 7) * 260 + pp];
            uint4* dst = (uint4*)(h1b + (long)gp * 64 + (cid & 3) * 16);
            dst[0] = A;
            dst[1] = Bv;
        }
    }
}

// ---- vectorized stats over row-major bf16 buffer: uint4 loads (8 ch/thread) ----
// Requires C in {64,128}; stride (gridDim*2048) % C == 0 so each thread's ch-block is fixed.
__global__ __launch_bounds__(256) void k_stats_v(const unsigned short* __restrict__ buf,
        long T, int C, float* __restrict__ out) {
    int t = threadIdx.x;
    long base = ((long)blockIdx.x * 256 + t) * 8;
    long stride = (long)gridDim.x * 2048;
    float s[8], q[8];
#pragma unroll
    for (int j = 0; j < 8; j++) { s[j] = 0.f; q[j] = 0.f; }
    for (long i = base; i < T; i += stride) {
        ABu u;
        u.q = *(const uint4*)(buf + i);
#pragma unroll
        for (int j = 0; j < 8; j++) {
            float v = bf2f(u.us[j]);
            s[j] += v;
            q[j] = fmaf(v, v, q[j]);
        }
    }
    __shared__ float ls[2048], lq[2048];
#pragma unroll
    for (int j = 0; j < 8; j++) { ls[t * 8 + j] = s[j]; lq[t * 8 + j] = q[j]; }
    __syncthreads();
    if (t < C) {
        int g = t >> 3, j = t & 7;
        int step = C >> 3;                // contributors: tid ≡ g (mod C/8)
        float ss = 0.f, qq = 0.f;
        for (int tid = g; tid < 256; tid += step) {
            ss += ls[tid * 8 + j];
            qq += lq[tid * 8 + j];
        }
        atomicAdd(&out[t], ss);
        atomicAdd(&out[C + t], qq);
    }
}

// ---- GEMM2 via MFMA (BN1 coefs computed inline from st1) ----
__global__ __launch_bounds__(256, 2) void k_gemm2_mfma(const unsigned short* __restrict__ h1b,
        const float* __restrict__ w2, const float* __restrict__ st1,
        const float* __restrict__ g1, const float* __restrict__ b1g, float invn,
        unsigned short* __restrict__ h2b, int N) {
    int lane = threadIdx.x & 63;
    int c = lane & 15, quad = lane >> 4;
    int wid = (blockIdx.x * 256 + threadIdx.x) >> 6;
    int nw = gridDim.x * 4;
    bf16x8_t Bf[8][2];
#pragma unroll
    for (int tt = 0; tt < 8; tt++)
#pragma unroll
        for (int kc = 0; kc < 2; kc++) {
            const float* wr = w2 + (tt * 16 + c) * 64 + kc * 32 + quad * 8;
            float4 w0 = *(const float4*)wr;
            float4 w1 = *(const float4*)(wr + 4);
            ABu tmp;
            tmp.us[0] = f2bf(w0.x); tmp.us[1] = f2bf(w0.y);
            tmp.us[2] = f2bf(w0.z); tmp.us[3] = f2bf(w0.w);
            tmp.us[4] = f2bf(w1.x); tmp.us[5] = f2bf(w1.y);
            tmp.us[6] = f2bf(w1.z); tmp.us[7] = f2bf(w1.w);
            Bf[tt][kc] = tmp.bf;
        }
    float a1[16], b1[16];
#pragma unroll
    for (int kc = 0; kc < 2; kc++)
#pragma unroll
        for (int j = 0; j < 8; j++) {
            int ch = kc * 32 + quad * 8 + j;
            bn_ab(st1, g1, b1g, 64, ch, invn, a1[kc * 8 + j], b1[kc * 8 + j]);
        }
    int ntiles = (N + 15) >> 4;
    for (int tile = wid; tile < ntiles; tile += nw) {
        int p0 = tile * 16;
        int pa = min(p0 + c, N - 1);
        bf16x8_t Af[2];
#pragma unroll
        for (int kc = 0; kc < 2; kc++) {
            ABu u;
            u.q = *(const uint4*)(h1b + (long)pa * 64 + kc * 32 + quad * 8);
            ABu o;
#pragma unroll
            for (int j = 0; j < 8; j++)
                o.us[j] = f2bf(bnr(bf2f(u.us[j]), a1[kc * 8 + j], b1[kc * 8 + j]));
            Af[kc] = o.bf;
        }
        f32x4_t acc[8];
#pragma unroll
        for (int tt = 0; tt < 8; tt++) acc[tt] = (f32x4_t){0.f, 0.f, 0.f, 0.f};
#pragma unroll
        for (int tt = 0; tt < 8; tt++) {
            acc[tt] = __builtin_amdgcn_mfma_f32_16x16x32_bf16(Af[0], Bf[tt][0], acc[tt], 0, 0, 0);
            acc[tt] = __builtin_amdgcn_mfma_f32_16x16x32_bf16(Af[1], Bf[tt][1], acc[tt], 0, 0, 0);
        }
#pragma unroll
        for (int tt = 0; tt < 8; tt++)
#pragma unroll
            for (int r = 0; r < 4; r++) {
                int pr = p0 + quad * 4 + r;
                if (pr < N) h2b[(long)pr * 128 + tt * 16 + c] = f2bf(acc[tt][r]);
            }
    }
}

// ---- scatter-max into dense cyl grid; one wave per point (lane = channel) ----
__global__ __launch_bounds__(256) void k_cylmax4(const unsigned short* __restrict__ h2b,
        const float* __restrict__ st2, const float* __restrict__ g2,
        const float* __restrict__ b2g, float invn, const float* __restrict__ pts,
        const float* __restrict__ cylidx, unsigned int* __restrict__ grid, int N) {
    int t = threadIdx.x, lane = t & 63, w = t >> 6;
    int p = blockIdx.x * 4 + w;
    if (p >= N) return;
    float a, bb;
    bn_ab(st2, g2, b2g, 128, lane, invn, a, bb);
    float v = bnr(bf2f(h2b[(long)p * 128 + lane]), a, bb);
    int b = (int)pts[p * 5];
    int cx = (int)floorf(cylidx[p * 2]);
    int cy = (int)floorf(cylidx[p * 2 + 1]);
    unsigned int* cell = grid + (((long)b * 512 + cx) * 48 + cy) * 64;
    if (v > 0.f) {
        unsigned uv = __float_as_uint(v);
        unsigned cur = cell[lane];
        if (uv > cur) atomicMax(&cell[lane], uv);
    }
}

// ---- 3x3 conv, LDS-staged implicit-GEMM MFMA ----
// block = 768 thr (12 waves: 3 segs x 4 oc-blocks), computes 2 output rows.
// Stages 4 rows x 50 px (fp32 grid -> bf16 LDS, XOR-swizzled chunks for bank uniformity).
__global__ __launch_bounds__(768) void k_conv_lds(const float* __restrict__ grid,
        const unsigned short* __restrict__ wctb, unsigned short* __restrict__ cb) {
    __shared__ unsigned short in_s[4 * 50 * 64];   // [row4][px][chunk^swz][8ch]
    __shared__ unsigned short ob_s[2 * 48 * 64];
    int t = threadIdx.x;
    int lane = t & 63, wv = t >> 6;
    int n = lane & 15, quad = lane >> 4;
    int seg = wv >> 2, tt = wv & 3;
    int blk = blockIdx.x;
    int b = blk >> 8, r0 = (blk & 255) * 2;
    // preload all 18 weight fragments into VGPRs
    bf16x8_t Bf[9][2];
    const unsigned short* wb = wctb + quad * 512 + (tt * 16 + n) * 8;
#pragma unroll
    for (int tap = 0; tap < 9; tap++)
#pragma unroll
        for (int kc = 0; kc < 2; kc++) {
            ABu u;
            u.q = *(const uint4*)(wb + (tap * 2 + kc) * 2048);
            Bf[tap][kc] = u.bf;
        }
    // stage 4 rows x 50 px x 64 ch (1600 16B-chunks)
    for (int c = t; c < 1600; c += 768) {
        int row4 = c / 400;
        int rem = c % 400;
        int px = rem >> 3, ch8 = rem & 7;
        int gr = r0 + row4 - 1, gw = px - 1;
        ABu o;
        if (gr >= 0 && gr < 512 && gw >= 0 && gw < 48) {
            const float* src = grid + (((long)b * 512 + gr) * 48 + gw) * 64 + ch8 * 8;
            float4 v0 = *(const float4*)src;
            float4 v1 = *(const float4*)(src + 4);
            o.us[0] = f2bf(v0.x); o.us[1] = f2bf(v0.y); o.us[2] = f2bf(v0.z); o.us[3] = f2bf(v0.w);
            o.us[4] = f2bf(v1.x); o.us[5] = f2bf(v1.y); o.us[6] = f2bf(v1.z); o.us[7] = f2bf(v1.w);
        } else {
            o.q = make_uint4(0, 0, 0, 0);
        }
        *(uint4*)&in_s[(row4 * 50 + px) * 64 + ((ch8 ^ (px & 7)) << 3)] = o.q;
    }
    __syncthreads();
    for (int rr = 0; rr < 2; rr++) {
        f32x4_t acc0 = (f32x4_t){0.f, 0.f, 0.f, 0.f};
        f32x4_t acc1 = (f32x4_t){0.f, 0.f, 0.f, 0.f};
#pragma unroll
        for (int tap = 0; tap < 9; tap++) {
            int row4 = tap / 3 + rr;
            int lpx = seg * 16 + n + tap % 3;
            const unsigned short* base = &in_s[(row4 * 50 + lpx) * 64];
            ABu a0, a1;
            a0.q = *(const uint4*)(base + ((quad ^ (lpx & 7)) << 3));
            a1.q = *(const uint4*)(base + (((4 + quad) ^ (lpx & 7)) << 3));
            acc0 = __builtin_amdgcn_mfma_f32_16x16x32_bf16(a0.bf, Bf[tap][0], acc0, 0, 0, 0);
            acc1 = __builtin_amdgcn_mfma_f32_16x16x32_bf16(a1.bf, Bf[tap][1], acc1, 0, 0, 0);
        }
#pragma unroll
        for (int r2 = 0; r2 < 4; r2++) {
            int px = seg * 16 + quad * 4 + r2;
            ob_s[(rr * 48 + px) * 64 + tt * 16 + n] = f2bf(acc0[r2] + acc1[r2]);
        }
    }
    __syncthreads();
    // coalesced write-out: 2 rows x 48 px x 64 ch = 768 uint4
    unsigned short* dst = cb + ((long)b * 512 + r0) * 48 * 64;
    *(uint4*)(dst + t * 8) = *(const uint4*)(ob_s + t * 8);
}

// ---- bilinear gather + GEMM3 via MFMA -> h3 row-major bf16 (BN coefs inline) ----
__global__ __launch_bounds__(256, 2) void k_gather3_mfma(const unsigned short* __restrict__ h2b,
        const unsigned short* __restrict__ convb, const float* __restrict__ st2,
        const float* __restrict__ g2, const float* __restrict__ b2g,
        const float* __restrict__ stC, const float* __restrict__ gc,
        const float* __restrict__ bcg, float invn, float invnC,
        const float* __restrict__ cylidx, const float* __restrict__ pts,
        const float* __restrict__ w3, unsigned short* __restrict__ h3b, int N) {
    int lane = threadIdx.x & 63;
    int c = lane & 15, quad = lane >> 4;
    int wid = (blockIdx.x * 256 + threadIdx.x) >> 6;
    int nw = gridDim.x * 4;
    bf16x8_t Bf[4][4];
#pragma unroll
    for (int tt = 0; tt < 4; tt++)
#pragma unroll
        for (int kc = 0; kc < 4; kc++) {
            const float* wr = w3 + (tt * 16 + c) * 128 + kc * 32 + quad * 8;
            float4 w0 = *(const float4*)wr;
            float4 w1 = *(const float4*)(wr + 4);
            ABu tmp;
            tmp.us[0] = f2bf(w0.x); tmp.us[1] = f2bf(w0.y);
            tmp.us[2] = f2bf(w0.z); tmp.us[3] = f2bf(w0.w);
            tmp.us[4] = f2bf(w1.x); tmp.us[5] = f2bf(w1.y);
            tmp.us[6] = f2bf(w1.z); tmp.us[7] = f2bf(w1.w);
            Bf[tt][kc] = tmp.bf;
        }
    float a2[16], b2[16], aC[16], bC[16];
#pragma unroll
    for (int kc = 0; kc < 2; kc++)
#pragma unroll
        for (int j = 0; j < 8; j++) {
            int kk = kc * 32 + quad * 8 + j;
            bn_ab(st2, g2, b2g, 128, 64 + kk, invn, a2[kc * 8 + j], b2[kc * 8 + j]);
            bn_ab(stC, gc, bcg, 64, kk, invnC, aC[kc * 8 + j], bC[kc * 8 + j]);
        }
    int ntiles = (N + 15) >> 4;
    for (int tile = wid; tile < ntiles; tile += nw) {
        int p0 = tile * 16;
        int p = min(p0 + c, N - 1);
        float yq = cylidx[p * 2], xq = cylidx[p * 2 + 1];
        int b = (int)pts[p * 5];
        int xf = (int)floorf(xq), yf = (int)floorf(yq);
        int x0 = min(max(xf, 0), 47);
        int x1 = min(max(xf + 1, 0), 47);
        int y0 = min(max(yf, 0), 511);
        int y1 = min(max(yf + 1, 0), 511);
        float x0f = (float)x0, x1f = (float)x1, y0f = (float)y0, y1f = (float)y1;
        float wa = (x1f - xq) * (y1f - yq);
        float wb = (x1f - xq) * (yq - y0f);
        float wc2 = (xq - x0f) * (y1f - yq);
        float wd = (xq - x0f) * (yq - y0f);
        const unsigned short* Ia = convb + (((long)b * 512 + y0) * 48 + x0) * 64;
        const unsigned short* Ib = convb + (((long)b * 512 + y1) * 48 + x0) * 64;
        const unsigned short* Ic = convb + (((long)b * 512 + y0) * 48 + x1) * 64;
        const unsigned short* Id = convb + (((long)b * 512 + y1) * 48 + x1) * 64;
        bf16x8_t Af[4];
#pragma unroll
        for (int kc = 0; kc < 2; kc++) {
            ABu u;
            u.q = *(const uint4*)(h2b + (long)p * 128 + 64 + kc * 32 + quad * 8);
            ABu o;
#pragma unroll
            for (int j = 0; j < 8; j++)
                o.us[j] = f2bf(bnr(bf2f(u.us[j]), a2[kc * 8 + j], b2[kc * 8 + j]));
            Af[kc] = o.bf;
        }
#pragma unroll
        for (int kc = 0; kc < 2; kc++) {
            int cbo = kc * 32 + quad * 8;
            ABu ua, ub, uc, ud;
            ua.q = *(const uint4*)(Ia + cbo);
            ub.q = *(const uint4*)(Ib + cbo);
            uc.q = *(const uint4*)(Ic + cbo);
            ud.q = *(const uint4*)(Id + cbo);
            ABu o;
#pragma unroll
            for (int j = 0; j < 8; j++) {
                float aa = aC[kc * 8 + j], bbv = bC[kc * 8 + j];
                float v = wa * bnr(bf2f(ua.us[j]), aa, bbv) + wb * bnr(bf2f(ub.us[j]), aa, bbv)
                        + wc2 * bnr(bf2f(uc.us[j]), aa, bbv) + wd * bnr(bf2f(ud.us[j]), aa, bbv);
                o.us[j] = f2bf(v);
            }
            Af[2 + kc] = o.bf;
        }
        f32x4_t acc[4];
#pragma unroll
        for (int tt = 0; tt < 4; tt++) acc[tt] = (f32x4_t){0.f, 0.f, 0.f, 0.f};
#pragma unroll
        for (int tt = 0; tt < 4; tt++)
#pragma unroll
            for (int kc = 0; kc < 4; kc++)
                acc[tt] = __builtin_amdgcn_mfma_f32_16x16x32_bf16(Af[kc], Bf[tt][kc], acc[tt], 0, 0, 0);
#pragma unroll
        for (int tt = 0; tt < 4; tt++)
#pragma unroll
            for (int r = 0; r < 4; r++) {
                int pr = p0 + quad * 4 + r;
                if (pr < N) h3b[(long)pr * 64 + tt * 16 + c] = f2bf(acc[tt][r]);
            }
    }
}

// ---- final BN-ReLU -> out_fea fp32 + bev scatter-max + voxel coords ----
__global__ __launch_bounds__(256) void k_out_tile3(const unsigned short* __restrict__ h3b,
        const float* __restrict__ st3, const float* __restrict__ g3,
        const float* __restrict__ b3g, float invn, const int* __restrict__ binv,
        float* __restrict__ out_fea, unsigned int* __restrict__ out_bev,
        const int* __restrict__ bcoords, float* __restrict__ out_vc, int Nb, int N) {
    int t = threadIdx.x, lane = t & 63, w = t >> 6;
    long gid = (long)blockIdx.x * 256 + t;
    if (gid < Nb) {
        int cc = bcoords[gid];
        int vb = cc / BEV_SXY;
        int rem = cc % BEV_SXY;
        int vx = rem / BEV_SY;
        int vy = rem % BEV_SY;
        out_vc[gid * 4 + 0] = (float)vb;
        out_vc[gid * 4 + 1] = 0.f;
        out_vc[gid * 4 + 2] = (float)vy;
        out_vc[gid * 4 + 3] = (float)vx;
    }
    int p = blockIdx.x * 4 + w;
    if (p >= N) return;
    float a, bb;
    bn_ab(st3, g3, b3g, 64, lane, invn, a, bb);
    float v = bnr(bf2f(h3b[(long)p * 64 + lane]), a, bb);
    out_fea[(long)p * 64 + lane] = v;
    int bi = binv[p];
    if (v > 0.f) {
        unsigned uv = __float_as_uint(v);
        unsigned* cell = out_bev + (long)bi * 64;
        unsigned cur = cell[lane];
        if (uv > cur) atomicMax(&cell[lane], uv);
    }
}

extern "C" void kernel_launch(void* const* d_in, const int* in_sizes, int n_in,
                              void* d_out, int out_size, void* d_ws, size_t ws_size,
                              hipStream_t stream) {
    const float* pts = (const float*)d_in[0];
    const float* pcyl = (const float*)d_in[1];
    const float* cylidx = (const float*)d_in[2];
    const float* bevidx = (const float*)d_in[3];
    const float* w1 = (const float*)d_in[4];
    const float* g1 = (const float*)d_in[5];
    const float* b1 = (const float*)d_in[6];
    const float* w2 = (const float*)d_in[7];
    const float* g2 = (const float*)d_in[8];
    const float* b2 = (const float*)d_in[9];
    const float* wc = (const float*)d_in[10];
    const float* gc = (const float*)d_in[11];
    const float* bc = (const float*)d_in[12];
    const float* w3 = (const float*)d_in[13];
    const float* g3 = (const float*)d_in[14];
    const float* b3 = (const float*)d_in[15];
    const int* binv = (const int*)d_in[16];
    const int* bcoords = (const int*)d_in[17];
    const int* cinv = (const int*)d_in[18];
    const int* ccoords = (const int*)d_in[19];
    int N = in_sizes[0] / 5;
    int Nb = in_sizes[17];
    int Nc = in_sizes[19];
    const int B = 4;
    const long GRIDSZ = (long)B * 512 * 48 * 64;
    float invN = 1.0f / (float)N;
    float invC = 1.0f / (float)(B * 512 * 48);

    char* wsb = (char*)d_ws;
    unsigned short* wctb = (unsigned short*)wsb;                      // 73728 B
    unsigned short* h2b = (unsigned short*)(wsb + 73728);             // 128N bf16
    unsigned short* h13b = (unsigned short*)(wsb + 73728 + 256L * N); // 64N bf16
    float* grid = (float*)(wsb + 73728 + 384L * N);                   // fp32 (atomics)
    unsigned short* convb = (unsigned short*)(grid + GRIDSZ);         // bf16 conv output
    float* bacc = (float*)(convb + GRIDSZ);
    float* cacc = bacc + 3L * Nb;
    float* stats = cacc + 3L * Nc;
    float* st1 = stats, *st2 = stats + 128, *st3 = stats + 384, *stC = stats + 512;

    float* out_fea = (float*)d_out;
    unsigned int* out_bev = (unsigned int*)((float*)d_out + (long)N * 64);
    float* out_vc = (float*)d_out + (long)N * 64 + (long)Nb * 64;

    hipMemsetAsync(grid, 0, (size_t)GRIDSZ * 4, stream);
    hipMemsetAsync(bacc, 0, (size_t)(3L * Nb + 3L * Nc + 768) * 4, stream);
    hipMemsetAsync(out_bev, 0, (size_t)Nb * 64 * 4, stream);

    int nb256 = (N + 255) / 256;
    k_scatter_sums<<<nb256, 256, 0, stream>>>(pts, pcyl, binv, cinv, wc, wctb, bacc, cacc, N, Nb, Nc);
    k_feat_gemm1<<<nb256, 256, 0, stream>>>(pts, pcyl, cylidx, bevidx, binv, cinv, bacc, cacc, w1, h13b, N, Nb, Nc);
    k_stats_v<<<512, 256, 0, stream>>>(h13b, 64L * N, 64, st1);
    k_gemm2_mfma<<<512, 256, 0, stream>>>(h13b, w2, st1, g1, b1, invN, h2b, N);
    k_stats_v<<<512, 256, 0, stream>>>(h2b, 128L * N, 128, st2);
    k_cylmax4<<<(N + 3) / 4, 256, 0, stream>>>(h2b, st2, g2, b2, invN, pts, cylidx, (unsigned int*)grid, N);
    k_conv_lds<<<1024, 768, 0, stream>>>(grid, wctb, convb);
    k_stats_v<<<512, 256, 0, stream>>>(convb, GRIDSZ, 64, stC);
    k_gather3_mfma<<<512, 256, 0, stream>>>(h2b, convb, st2, g2, b2, stC, gc, bc, invN, invC, cylidx, pts, w3, h13b, N);
    k_stats_v<<<512, 256, 0, stream>>>(h13b, 64L * N, 64, st3);
    k_out_tile3<<<(N + 3) / 4, 256, 0, stream>>>(h13b, st3, g3, b3, invN, binv, out_fea, out_bev, bcoords, out_vc, Nb, N);
}

// Round 7
// 462.681 us; speedup vs baseline: 3.4782x; 1.0554x over previous
//
#include <hip/hip_runtime.h>
#include <math.h>

#define BN_EPS 1e-3f

static constexpr float CR0 = -3.14159265f;
static constexpr float CR1 = -2.0f;
static constexpr float CVS0 = (float)((3.14159265 * 2.0) / 512.0);
static constexpr float CVS1 = (float)(6.0 / 48.0);
#define BEV_SXY (220 * 250)
#define BEV_SY 250

typedef __attribute__((ext_vector_type(8))) __bf16 bf16x8_t;
typedef __attribute__((ext_vector_type(4))) float f32x4_t;

union ABu { uint4 q; unsigned short us[8]; bf16x8_t bf; };

__device__ __forceinline__ float bnr(float x, float a, float b) {
    float v = fmaf(x, a, b);
    return v > 0.f ? v : 0.f;
}
__device__ __forceinline__ float bf2f(unsigned short u) {
    return __uint_as_float(((unsigned)u) << 16);
}
__device__ __forceinline__ unsigned short f2bf(float f) {
    unsigned u = __float_as_uint(f);
    u += 0x7FFFu + ((u >> 16) & 1u);
    return (unsigned short)(u >> 16);
}
__device__ __forceinline__ void bn_ab(const float* st, const float* g, const float* b,
                                      int C, int ch, float invn, float& a, float& bb) {
    float m = st[ch] * invn;
    float var = st[C + ch] * invn - m * m;
    a = g[ch] * rsqrtf(var + BN_EPS);
    bb = b[ch] - m * a;
}

// ---- segment sums (u64 fixed-point packed atomics) + conv-weight pre-pack ----
// bacc[2i]   += (1<<44) | round(x*2^20)        (cnt in hi 20b; x>0, carry-safe)
// bacc[2i+1] += round((y+40)*2^24)             (y+40>0)
// cacc[2i]   += (1<<44) | round((phi+pi)*2^24) (phi in (-pi/2,pi/2) since x>0)
// cacc[2i+1] += round((z+3)*2^24)              (z+3>0)
__global__ void k_scatter_sums(const float* __restrict__ pts, const float* __restrict__ pcyl,
                               const int* __restrict__ binv, const int* __restrict__ cinv,
                               const float* __restrict__ wc, unsigned short* __restrict__ wctb,
                               unsigned long long* __restrict__ bacc,
                               unsigned long long* __restrict__ cacc,
                               int N, int Nb, int Nc) {
    int p = blockIdx.x * blockDim.x + threadIdx.x;
    if (p < 9 * 4096) {
        int j = p & 7, oc = (p >> 3) & 63, quad = (p >> 9) & 3, kc = (p >> 11) & 1, tap = p >> 12;
        int ic = kc * 32 + quad * 8 + j;
        wctb[p] = f2bf(wc[((oc * 64 + ic) * 3 + tap / 3) * 3 + tap % 3]);
    }
    if (p >= N) return;
    float x = pts[p * 5 + 1], y = pts[p * 5 + 2];
    float ph = pcyl[p * 3 + 0], z = pcyl[p * 3 + 1];
    int bi = binv[p], ci = cinv[p];
    unsigned long long xa = (1ull << 44) + (unsigned long long)(x * 1048576.0f + 0.5f);
    unsigned long long ya = (unsigned long long)((y + 40.0f) * 16777216.0f + 0.5f);
    unsigned long long pa = (1ull << 44) + (unsigned long long)((ph + 3.14159265f) * 16777216.0f + 0.5f);
    unsigned long long za = (unsigned long long)((z + 3.0f) * 16777216.0f + 0.5f);
    atomicAdd(&bacc[2 * (long)bi], xa);
    atomicAdd(&bacc[2 * (long)bi + 1], ya);
    atomicAdd(&cacc[2 * (long)ci], pa);
    atomicAdd(&cacc[2 * (long)ci + 1], za);
}

// ---- 16-feat build + GEMM1 (16->64), h1 row-major bf16 via LDS transpose ----
__global__ __launch_bounds__(256) void k_feat_gemm1(const float* __restrict__ pts,
        const float* __restrict__ pcyl, const float* __restrict__ cylidx,
        const float* __restrict__ bevidx, const int* __restrict__ binv,
        const int* __restrict__ cinv, const unsigned long long* __restrict__ bacc,
        const unsigned long long* __restrict__ cacc, const float* __restrict__ w1,
        unsigned short* __restrict__ h1b, int N, int Nb, int Nc) {
    __shared__ float w1s[1024];
    __shared__ unsigned int tbuf[32 * 260];
    int t = threadIdx.x;
    for (int i = t; i < 1024; i += 256) w1s[i] = w1[i];
    __syncthreads();
    int p = blockIdx.x * 256 + t;
    int pc = min(p, N - 1);
    float x = pts[pc * 5 + 1], y = pts[pc * 5 + 2], z = pts[pc * 5 + 3], inten = pts[pc * 5 + 4];
    float ph = pcyl[pc * 3 + 0], zc = pcyl[pc * 3 + 1], rho = pcyl[pc * 3 + 2];
    float ci0 = cylidx[pc * 2 + 0], ci1 = cylidx[pc * 2 + 1];
    float bi0 = bevidx[pc * 2 + 0], bi1 = bevidx[pc * 2 + 1];
    float bc0 = floorf(bi0), bc1 = floorf(bi1);
    float cc0 = floorf(ci0), cc1 = floorf(ci1);
    int bv = binv[pc], cv = cinv[pc];
    const unsigned long long MASK44 = (1ull << 44) - 1ull;
    unsigned long long A = bacc[2 * (long)bv], Bq = bacc[2 * (long)bv + 1];
    float bcnt = (float)(A >> 44);
    float rb = 1.0f / bcnt;
    float bmx = (float)(A & MASK44) * (1.0f / 1048576.0f) * rb;
    float bmy = (float)Bq * (1.0f / 16777216.0f) * rb - 40.0f;
    unsigned long long Cq = cacc[2 * (long)cv], Dq = cacc[2 * (long)cv + 1];
    float ccnt = (float)(Cq >> 44);
    float rc = 1.0f / ccnt;
    float cmp = (float)(Cq & MASK44) * (1.0f / 16777216.0f) * rc - 3.14159265f;
    float cmz = (float)Dq * (1.0f / 16777216.0f) * rc - 3.0f;
    float f[16];
    f[0] = x; f[1] = y; f[2] = z;
    f[3] = ph; f[4] = zc; f[5] = rho;
    f[6] = x - ((bc0 + 0.5f) * 0.32f + 0.0f);
    f[7] = y - ((bc1 + 0.5f) * 0.32f + (-40.0f));
    f[8] = ph - ((cc0 + 0.5f) * CVS0 + CR0);
    f[9] = zc - ((cc1 + 0.5f) * CVS1 + CR1);
    f[10] = x - bmx; f[11] = y - bmy;
    f[12] = ph - cmp; f[13] = zc - cmz;
    f[14] = sqrtf(x * x + y * y + z * z);
    f[15] = inten;
    for (int c2 = 0; c2 < 32; c2++) {
        float s0 = 0.f, s1 = 0.f;
        const float* w0 = &w1s[(2 * c2) * 16];
        const float* w1p = &w1s[(2 * c2 + 1) * 16];
#pragma unroll
        for (int k = 0; k < 16; k++) {
            s0 = fmaf(f[k], w0[k], s0);
            s1 = fmaf(f[k], w1p[k], s1);
        }
        tbuf[c2 * 260 + t] = (unsigned)f2bf(s0) | ((unsigned)f2bf(s1) << 16);
    }
    __syncthreads();
#pragma unroll
    for (int r = 0; r < 4; r++) {
        int cid = t + 256 * r;
        int pp = cid >> 2;
        int gp = blockIdx.x * 256 + pp;
        if (gp < N) {
            int c2b = (cid & 3) * 8;
            uint4 A2, Bv;
            A2.x = tbuf[(c2b + 0) * 260 + pp];
            A2.y = tbuf[(c2b + 1) * 260 + pp];
            A2.z = tbuf[(c2b + 2) * 260 + pp];
            A2.w = tbuf[(c2b + 3) * 260 + pp];
            Bv.x = tbuf[(c2b + 4) * 260 + pp];
            Bv.y = tbuf[(c2b + 5) * 260 + pp];
            Bv.z = tbuf[(c2b + 6) * 260 + pp];
            Bv.w = tbuf[(c2b + 7) * 260 + pp];
            uint4* dst = (uint4*)(h1b + (long)gp * 64 + (cid & 3) * 16);
            dst[0] = A2;
            dst[1] = Bv;
        }
    }
}

// ---- vectorized stats over row-major bf16 buffer: uint4 loads (8 ch/thread) ----
__global__ __launch_bounds__(256) void k_stats_v(const unsigned short* __restrict__ buf,
        long T, int C, float* __restrict__ out) {
    int t = threadIdx.x;
    long base = ((long)blockIdx.x * 256 + t) * 8;
    long stride = (long)gridDim.x * 2048;
    float s[8], q[8];
#pragma unroll
    for (int j = 0; j < 8; j++) { s[j] = 0.f; q[j] = 0.f; }
    for (long i = base; i < T; i += stride) {
        ABu u;
        u.q = *(const uint4*)(buf + i);
#pragma unroll
        for (int j = 0; j < 8; j++) {
            float v = bf2f(u.us[j]);
            s[j] += v;
            q[j] = fmaf(v, v, q[j]);
        }
    }
    __shared__ float ls[2048], lq[2048];
#pragma unroll
    for (int j = 0; j < 8; j++) { ls[t * 8 + j] = s[j]; lq[t * 8 + j] = q[j]; }
    __syncthreads();
    if (t < C) {
        int g = t >> 3, j = t & 7;
        int step = C >> 3;
        float ss = 0.f, qq = 0.f;
        for (int tid = g; tid < 256; tid += step) {
            ss += ls[tid * 8 + j];
            qq += lq[tid * 8 + j];
        }
        atomicAdd(&out[t], ss);
        atomicAdd(&out[C + t], qq);
    }
}

// ---- GEMM2 via MFMA (BN1 coefs computed inline from st1) ----
__global__ __launch_bounds__(256, 2) void k_gemm2_mfma(const unsigned short* __restrict__ h1b,
        const float* __restrict__ w2, const float* __restrict__ st1,
        const float* __restrict__ g1, const float* __restrict__ b1g, float invn,
        unsigned short* __restrict__ h2b, int N) {
    int lane = threadIdx.x & 63;
    int c = lane & 15, quad = lane >> 4;
    int wid = (blockIdx.x * 256 + threadIdx.x) >> 6;
    int nw = gridDim.x * 4;
    bf16x8_t Bf[8][2];
#pragma unroll
    for (int tt = 0; tt < 8; tt++)
#pragma unroll
        for (int kc = 0; kc < 2; kc++) {
            const float* wr = w2 + (tt * 16 + c) * 64 + kc * 32 + quad * 8;
            float4 w0 = *(const float4*)wr;
            float4 w1 = *(const float4*)(wr + 4);
            ABu tmp;
            tmp.us[0] = f2bf(w0.x); tmp.us[1] = f2bf(w0.y);
            tmp.us[2] = f2bf(w0.z); tmp.us[3] = f2bf(w0.w);
            tmp.us[4] = f2bf(w1.x); tmp.us[5] = f2bf(w1.y);
            tmp.us[6] = f2bf(w1.z); tmp.us[7] = f2bf(w1.w);
            Bf[tt][kc] = tmp.bf;
        }
    float a1[16], b1[16];
#pragma unroll
    for (int kc = 0; kc < 2; kc++)
#pragma unroll
        for (int j = 0; j < 8; j++) {
            int ch = kc * 32 + quad * 8 + j;
            bn_ab(st1, g1, b1g, 64, ch, invn, a1[kc * 8 + j], b1[kc * 8 + j]);
        }
    int ntiles = (N + 15) >> 4;
    for (int tile = wid; tile < ntiles; tile += nw) {
        int p0 = tile * 16;
        int pa = min(p0 + c, N - 1);
        bf16x8_t Af[2];
#pragma unroll
        for (int kc = 0; kc < 2; kc++) {
            ABu u;
            u.q = *(const uint4*)(h1b + (long)pa * 64 + kc * 32 + quad * 8);
            ABu o;
#pragma unroll
            for (int j = 0; j < 8; j++)
                o.us[j] = f2bf(bnr(bf2f(u.us[j]), a1[kc * 8 + j], b1[kc * 8 + j]));
            Af[kc] = o.bf;
        }
        f32x4_t acc[8];
#pragma unroll
        for (int tt = 0; tt < 8; tt++) acc[tt] = (f32x4_t){0.f, 0.f, 0.f, 0.f};
#pragma unroll
        for (int tt = 0; tt < 8; tt++) {
            acc[tt] = __builtin_amdgcn_mfma_f32_16x16x32_bf16(Af[0], Bf[tt][0], acc[tt], 0, 0, 0);
            acc[tt] = __builtin_amdgcn_mfma_f32_16x16x32_bf16(Af[1], Bf[tt][1], acc[tt], 0, 0, 0);
        }
#pragma unroll
        for (int tt = 0; tt < 8; tt++)
#pragma unroll
            for (int r = 0; r < 4; r++) {
                int pr = p0 + quad * 4 + r;
                if (pr < N) h2b[(long)pr * 128 + tt * 16 + c] = f2bf(acc[tt][r]);
            }
    }
}

// ---- scatter-max into dense cyl grid; one wave per point (lane = channel) ----
__global__ __launch_bounds__(256) void k_cylmax4(const unsigned short* __restrict__ h2b,
        const float* __restrict__ st2, const float* __restrict__ g2,
        const float* __restrict__ b2g, float invn, const float* __restrict__ pts,
        const float* __restrict__ cylidx, unsigned int* __restrict__ grid, int N) {
    int t = threadIdx.x, lane = t & 63, w = t >> 6;
    int p = blockIdx.x * 4 + w;
    if (p >= N) return;
    float a, bb;
    bn_ab(st2, g2, b2g, 128, lane, invn, a, bb);
    float v = bnr(bf2f(h2b[(long)p * 128 + lane]), a, bb);
    int b = (int)pts[p * 5];
    int cx = (int)floorf(cylidx[p * 2]);
    int cy = (int)floorf(cylidx[p * 2 + 1]);
    unsigned int* cell = grid + (((long)b * 512 + cx) * 48 + cy) * 64;
    if (v > 0.f) {
        unsigned uv = __float_as_uint(v);
        unsigned cur = cell[lane];
        if (uv > cur) atomicMax(&cell[lane], uv);
    }
}

// ---- 3x3 conv, LDS-staged implicit-GEMM MFMA ----
__global__ __launch_bounds__(768) void k_conv_lds(const float* __restrict__ grid,
        const unsigned short* __restrict__ wctb, unsigned short* __restrict__ cb) {
    __shared__ unsigned short in_s[4 * 50 * 64];
    __shared__ unsigned short ob_s[2 * 48 * 64];
    int t = threadIdx.x;
    int lane = t & 63, wv = t >> 6;
    int n = lane & 15, quad = lane >> 4;
    int seg = wv >> 2, tt = wv & 3;
    int blk = blockIdx.x;
    int b = blk >> 8, r0 = (blk & 255) * 2;
    bf16x8_t Bf[9][2];
    const unsigned short* wb = wctb + quad * 512 + (tt * 16 + n) * 8;
#pragma unroll
    for (int tap = 0; tap < 9; tap++)
#pragma unroll
        for (int kc = 0; kc < 2; kc++) {
            ABu u;
            u.q = *(const uint4*)(wb + (tap * 2 + kc) * 2048);
            Bf[tap][kc] = u.bf;
        }
    for (int c = t; c < 1600; c += 768) {
        int row4 = c / 400;
        int rem = c % 400;
        int px = rem >> 3, ch8 = rem & 7;
        int gr = r0 + row4 - 1, gw = px - 1;
        ABu o;
        if (gr >= 0 && gr < 512 && gw >= 0 && gw < 48) {
            const float* src = grid + (((long)b * 512 + gr) * 48 + gw) * 64 + ch8 * 8;
            float4 v0 = *(const float4*)src;
            float4 v1 = *(const float4*)(src + 4);
            o.us[0] = f2bf(v0.x); o.us[1] = f2bf(v0.y); o.us[2] = f2bf(v0.z); o.us[3] = f2bf(v0.w);
            o.us[4] = f2bf(v1.x); o.us[5] = f2bf(v1.y); o.us[6] = f2bf(v1.z); o.us[7] = f2bf(v1.w);
        } else {
            o.q = make_uint4(0, 0, 0, 0);
        }
        *(uint4*)&in_s[(row4 * 50 + px) * 64 + ((ch8 ^ (px & 7)) << 3)] = o.q;
    }
    __syncthreads();
    for (int rr = 0; rr < 2; rr++) {
        f32x4_t acc0 = (f32x4_t){0.f, 0.f, 0.f, 0.f};
        f32x4_t acc1 = (f32x4_t){0.f, 0.f, 0.f, 0.f};
#pragma unroll
        for (int tap = 0; tap < 9; tap++) {
            int row4 = tap / 3 + rr;
            int lpx = seg * 16 + n + tap % 3;
            const unsigned short* base = &in_s[(row4 * 50 + lpx) * 64];
            ABu a0, a1;
            a0.q = *(const uint4*)(base + ((quad ^ (lpx & 7)) << 3));
            a1.q = *(const uint4*)(base + (((4 + quad) ^ (lpx & 7)) << 3));
            acc0 = __builtin_amdgcn_mfma_f32_16x16x32_bf16(a0.bf, Bf[tap][0], acc0, 0, 0, 0);
            acc1 = __builtin_amdgcn_mfma_f32_16x16x32_bf16(a1.bf, Bf[tap][1], acc1, 0, 0, 0);
        }
#pragma unroll
        for (int r2 = 0; r2 < 4; r2++) {
            int px = seg * 16 + quad * 4 + r2;
            ob_s[(rr * 48 + px) * 64 + tt * 16 + n] = f2bf(acc0[r2] + acc1[r2]);
        }
    }
    __syncthreads();
    unsigned short* dst = cb + ((long)b * 512 + r0) * 48 * 64;
    *(uint4*)(dst + t * 8) = *(const uint4*)(ob_s + t * 8);
}

// ---- bilinear gather + GEMM3 via MFMA -> h3 row-major bf16 (BN coefs inline) ----
__global__ __launch_bounds__(256, 2) void k_gather3_mfma(const unsigned short* __restrict__ h2b,
        const unsigned short* __restrict__ convb, const float* __restrict__ st2,
        const float* __restrict__ g2, const float* __restrict__ b2g,
        const float* __restrict__ stC, const float* __restrict__ gc,
        const float* __restrict__ bcg, float invn, float invnC,
        const float* __restrict__ cylidx, const float* __restrict__ pts,
        const float* __restrict__ w3, unsigned short* __restrict__ h3b, int N) {
    int lane = threadIdx.x & 63;
    int c = lane & 15, quad = lane >> 4;
    int wid = (blockIdx.x * 256 + threadIdx.x) >> 6;
    int nw = gridDim.x * 4;
    bf16x8_t Bf[4][4];
#pragma unroll
    for (int tt = 0; tt < 4; tt++)
#pragma unroll
        for (int kc = 0; kc < 4; kc++) {
            const float* wr = w3 + (tt * 16 + c) * 128 + kc * 32 + quad * 8;
            float4 w0 = *(const float4*)wr;
            float4 w1 = *(const float4*)(wr + 4);
            ABu tmp;
            tmp.us[0] = f2bf(w0.x); tmp.us[1] = f2bf(w0.y);
            tmp.us[2] = f2bf(w0.z); tmp.us[3] = f2bf(w0.w);
            tmp.us[4] = f2bf(w1.x); tmp.us[5] = f2bf(w1.y);
            tmp.us[6] = f2bf(w1.z); tmp.us[7] = f2bf(w1.w);
            Bf[tt][kc] = tmp.bf;
        }
    float a2[16], b2[16], aC[16], bC[16];
#pragma unroll
    for (int kc = 0; kc < 2; kc++)
#pragma unroll
        for (int j = 0; j < 8; j++) {
            int kk = kc * 32 + quad * 8 + j;
            bn_ab(st2, g2, b2g, 128, 64 + kk, invn, a2[kc * 8 + j], b2[kc * 8 + j]);
            bn_ab(stC, gc, bcg, 64, kk, invnC, aC[kc * 8 + j], bC[kc * 8 + j]);
        }
    int ntiles = (N + 15) >> 4;
    for (int tile = wid; tile < ntiles; tile += nw) {
        int p0 = tile * 16;
        int p = min(p0 + c, N - 1);
        float yq = cylidx[p * 2], xq = cylidx[p * 2 + 1];
        int b = (int)pts[p * 5];
        int xf = (int)floorf(xq), yf = (int)floorf(yq);
        int x0 = min(max(xf, 0), 47);
        int x1 = min(max(xf + 1, 0), 47);
        int y0 = min(max(yf, 0), 511);
        int y1 = min(max(yf + 1, 0), 511);
        float x0f = (float)x0, x1f = (float)x1, y0f = (float)y0, y1f = (float)y1;
        float wa = (x1f - xq) * (y1f - yq);
        float wb = (x1f - xq) * (yq - y0f);
        float wc2 = (xq - x0f) * (y1f - yq);
        float wd = (xq - x0f) * (yq - y0f);
        const unsigned short* Ia = convb + (((long)b * 512 + y0) * 48 + x0) * 64;
        const unsigned short* Ib = convb + (((long)b * 512 + y1) * 48 + x0) * 64;
        const unsigned short* Ic = convb + (((long)b * 512 + y0) * 48 + x1) * 64;
        const unsigned short* Id = convb + (((long)b * 512 + y1) * 48 + x1) * 64;
        bf16x8_t Af[4];
#pragma unroll
        for (int kc = 0; kc < 2; kc++) {
            ABu u;
            u.q = *(const uint4*)(h2b + (long)p * 128 + 64 + kc * 32 + quad * 8);
            ABu o;
#pragma unroll
            for (int j = 0; j < 8; j++)
                o.us[j] = f2bf(bnr(bf2f(u.us[j]), a2[kc * 8 + j], b2[kc * 8 + j]));
            Af[kc] = o.bf;
        }
#pragma unroll
        for (int kc = 0; kc < 2; kc++) {
            int cbo = kc * 32 + quad * 8;
            ABu ua, ub, uc, ud;
            ua.q = *(const uint4*)(Ia + cbo);
            ub.q = *(const uint4*)(Ib + cbo);
            uc.q = *(const uint4*)(Ic + cbo);
            ud.q = *(const uint4*)(Id + cbo);
            ABu o;
#pragma unroll
            for (int j = 0; j < 8; j++) {
                float aa = aC[kc * 8 + j], bbv = bC[kc * 8 + j];
                float v = wa * bnr(bf2f(ua.us[j]), aa, bbv) + wb * bnr(bf2f(ub.us[j]), aa, bbv)
                        + wc2 * bnr(bf2f(uc.us[j]), aa, bbv) + wd * bnr(bf2f(ud.us[j]), aa, bbv);
                o.us[j] = f2bf(v);
            }
            Af[2 + kc] = o.bf;
        }
        f32x4_t acc[4];
#pragma unroll
        for (int tt = 0; tt < 4; tt++) acc[tt] = (f32x4_t){0.f, 0.f, 0.f, 0.f};
#pragma unroll
        for (int tt = 0; tt < 4; tt++)
#pragma unroll
            for (int kc = 0; kc < 4; kc++)
                acc[tt] = __builtin_amdgcn_mfma_f32_16x16x32_bf16(Af[kc], Bf[tt][kc], acc[tt], 0, 0, 0);
#pragma unroll
        for (int tt = 0; tt < 4; tt++)
#pragma unroll
            for (int r = 0; r < 4; r++) {
                int pr = p0 + quad * 4 + r;
                if (pr < N) h3b[(long)pr * 64 + tt * 16 + c] = f2bf(acc[tt][r]);
            }
    }
}

// ---- final BN-ReLU -> out_fea fp32 + bev scatter-max + voxel coords ----
__global__ __launch_bounds__(256) void k_out_tile3(const unsigned short* __restrict__ h3b,
        const float* __restrict__ st3, const float* __restrict__ g3,
        const float* __restrict__ b3g, float invn, const int* __restrict__ binv,
        float* __restrict__ out_fea, unsigned int* __restrict__ out_bev,
        const int* __restrict__ bcoords, float* __restrict__ out_vc, int Nb, int N) {
    int t = threadIdx.x, lane = t & 63, w = t >> 6;
    long gid = (long)blockIdx.x * 256 + t;
    if (gid < Nb) {
        int cc = bcoords[gid];
        int vb = cc / BEV_SXY;
        int rem = cc % BEV_SXY;
        int vx = rem / BEV_SY;
        int vy = rem % BEV_SY;
        out_vc[gid * 4 + 0] = (float)vb;
        out_vc[gid * 4 + 1] = 0.f;
        out_vc[gid * 4 + 2] = (float)vy;
        out_vc[gid * 4 + 3] = (float)vx;
    }
    int p = blockIdx.x * 4 + w;
    if (p >= N) return;
    float a, bb;
    bn_ab(st3, g3, b3g, 64, lane, invn, a, bb);
    float v = bnr(bf2f(h3b[(long)p * 64 + lane]), a, bb);
    out_fea[(long)p * 64 + lane] = v;
    int bi = binv[p];
    if (v > 0.f) {
        unsigned uv = __float_as_uint(v);
        unsigned* cell = out_bev + (long)bi * 64;
        unsigned cur = cell[lane];
        if (uv > cur) atomicMax(&cell[lane], uv);
    }
}

extern "C" void kernel_launch(void* const* d_in, const int* in_sizes, int n_in,
                              void* d_out, int out_size, void* d_ws, size_t ws_size,
                              hipStream_t stream) {
    const float* pts = (const float*)d_in[0];
    const float* pcyl = (const float*)d_in[1];
    const float* cylidx = (const float*)d_in[2];
    const float* bevidx = (const float*)d_in[3];
    const float* w1 = (const float*)d_in[4];
    const float* g1 = (const float*)d_in[5];
    const float* b1 = (const float*)d_in[6];
    const float* w2 = (const float*)d_in[7];
    const float* g2 = (const float*)d_in[8];
    const float* b2 = (const float*)d_in[9];
    const float* wc = (const float*)d_in[10];
    const float* gc = (const float*)d_in[11];
    const float* bc = (const float*)d_in[12];
    const float* w3 = (const float*)d_in[13];
    const float* g3 = (const float*)d_in[14];
    const float* b3 = (const float*)d_in[15];
    const int* binv = (const int*)d_in[16];
    const int* bcoords = (const int*)d_in[17];
    const int* cinv = (const int*)d_in[18];
    const int* ccoords = (const int*)d_in[19];
    int N = in_sizes[0] / 5;
    int Nb = in_sizes[17];
    int Nc = in_sizes[19];
    const int B = 4;
    const long GRIDSZ = (long)B * 512 * 48 * 64;
    float invN = 1.0f / (float)N;
    float invC = 1.0f / (float)(B * 512 * 48);

    char* wsb = (char*)d_ws;
    unsigned short* wctb = (unsigned short*)wsb;                      // 73728 B
    unsigned short* h2b = (unsigned short*)(wsb + 73728);             // 128N bf16
    unsigned short* h13b = (unsigned short*)(wsb + 73728 + 256L * N); // 64N bf16
    float* grid = (float*)(wsb + 73728 + 384L * N);                   // fp32 (atomics)
    unsigned short* convb = (unsigned short*)(grid + GRIDSZ);         // bf16 conv output
    unsigned long long* bacc = (unsigned long long*)(convb + GRIDSZ); // 2*Nb u64
    unsigned long long* cacc = bacc + 2L * Nb;                        // 2*Nc u64
    float* stats = (float*)(cacc + 2L * Nc);                          // 768 floats
    float* st1 = stats, *st2 = stats + 128, *st3 = stats + 384, *stC = stats + 512;

    float* out_fea = (float*)d_out;
    unsigned int* out_bev = (unsigned int*)((float*)d_out + (long)N * 64);
    float* out_vc = (float*)d_out + (long)N * 64 + (long)Nb * 64;

    hipMemsetAsync(grid, 0, (size_t)GRIDSZ * 4, stream);
    hipMemsetAsync(bacc, 0, (size_t)((2L * Nb + 2L * Nc) * 8 + 768 * 4), stream);
    hipMemsetAsync(out_bev, 0, (size_t)Nb * 64 * 4, stream);

    int nb256 = (N + 255) / 256;
    k_scatter_sums<<<nb256, 256, 0, stream>>>(pts, pcyl, binv, cinv, wc, wctb, bacc, cacc, N, Nb, Nc);
    k_feat_gemm1<<<nb256, 256, 0, stream>>>(pts, pcyl, cylidx, bevidx, binv, cinv, bacc, cacc, w1, h13b, N, Nb, Nc);
    k_stats_v<<<512, 256, 0, stream>>>(h13b, 64L * N, 64, st1);
    k_gemm2_mfma<<<512, 256, 0, stream>>>(h13b, w2, st1, g1, b1, invN, h2b, N);
    k_stats_v<<<512, 256, 0, stream>>>(h2b, 128L * N, 128, st2);
    k_cylmax4<<<(N + 3) / 4, 256, 0, stream>>>(h2b, st2, g2, b2, invN, pts, cylidx, (unsigned int*)grid, N);
    k_conv_lds<<<1024, 768, 0, stream>>>(grid, wctb, convb);
    k_stats_v<<<512, 256, 0, stream>>>(convb, GRIDSZ, 64, stC);
    k_gather3_mfma<<<512, 256, 0, stream>>>(h2b, convb, st2, g2, b2, stC, gc, bc, invN, invC, cylidx, pts, w3, h13b, N);
    k_stats_v<<<512, 256, 0, stream>>>(h13b, 64L * N, 64, st3);
    k_out_tile3<<<(N + 3) / 4, 256, 0, stream>>>(h13b, st3, g3, b3, invN, binv, out_fea, out_bev, bcoords, out_vc, Nb, N);
}